// Round 1
// baseline (3469.328 us; speedup 1.0000x reference)
//
#include <hip/hip_runtime.h>
#include <math.h>

// ---------------------------------------------------------------------------
// Encoder conv: k=4, stride=2, pad=1. Thread computes 2x2 spatial x 4 co.
// Weights staged in LDS as [tap][ci][co4] so one float4 read feeds 16 FMAs.
// ---------------------------------------------------------------------------
template<int CIN>
__global__ __launch_bounds__(256) void conv_k4s2(
    const float* __restrict__ in, const float* __restrict__ w,
    const float* __restrict__ bias, float* __restrict__ out,
    int H, int W, int Cout, int quadsPerImg, int totalQuads, int relu)
{
    const int H2 = H >> 1, W2 = W >> 1;
    const int co0 = blockIdx.y * 4;
    __shared__ float ws[16 * CIN * 4];
    for (int i = threadIdx.x; i < 16 * CIN * 4; i += 256) {
        int c   = i & 3;
        int ci  = (i >> 2) % CIN;
        int tap = i / (4 * CIN);
        float v = 0.f;
        if (co0 + c < Cout)
            v = w[(((size_t)(co0 + c) * CIN + ci) << 4) + tap];  // OIHW
        ws[i] = v;
    }
    __syncthreads();
    int q = blockIdx.x * 256 + threadIdx.x;
    if (q >= totalQuads) return;
    int n  = q / quadsPerImg;
    int ql = q - n * quadsPerImg;
    int Wq = W2 >> 1;
    int qy = ql / Wq, qx = ql - qy * Wq;
    int oy0 = qy << 1, ox0 = qx << 1;
    int iy0 = (oy0 << 1) - 1, ix0 = (ox0 << 1) - 1;  // input window origin

    float acc[2][2][4];
    #pragma unroll
    for (int sy = 0; sy < 2; ++sy)
        #pragma unroll
        for (int sx = 0; sx < 2; ++sx)
            #pragma unroll
            for (int c = 0; c < 4; ++c) acc[sy][sx][c] = 0.f;

    const float* inn = in + (size_t)n * CIN * H * W;
    for (int ci = 0; ci < CIN; ++ci) {
        const float* ip = inn + (size_t)ci * H * W;
        float xv[6][6];
        #pragma unroll
        for (int r = 0; r < 6; ++r) {
            int iy = iy0 + r;
            bool ry = (iy >= 0) && (iy < H);
            #pragma unroll
            for (int cc = 0; cc < 6; ++cc) {
                int ix = ix0 + cc;
                xv[r][cc] = (ry && ix >= 0 && ix < W) ? ip[iy * W + ix] : 0.f;
            }
        }
        #pragma unroll
        for (int ky = 0; ky < 4; ++ky) {
            #pragma unroll
            for (int kx = 0; kx < 4; ++kx) {
                const float4 wv = *(const float4*)&ws[((((ky << 2) + kx) * CIN + ci) << 2)];
                #pragma unroll
                for (int sy = 0; sy < 2; ++sy) {
                    #pragma unroll
                    for (int sx = 0; sx < 2; ++sx) {
                        float xval = xv[(sy << 1) + ky][(sx << 1) + kx];
                        acc[sy][sx][0] = fmaf(xval, wv.x, acc[sy][sx][0]);
                        acc[sy][sx][1] = fmaf(xval, wv.y, acc[sy][sx][1]);
                        acc[sy][sx][2] = fmaf(xval, wv.z, acc[sy][sx][2]);
                        acc[sy][sx][3] = fmaf(xval, wv.w, acc[sy][sx][3]);
                    }
                }
            }
        }
    }
    #pragma unroll
    for (int c = 0; c < 4; ++c) {
        int co = co0 + c;
        if (co >= Cout) break;
        float bv = bias[co];
        #pragma unroll
        for (int sy = 0; sy < 2; ++sy) {
            #pragma unroll
            for (int sx = 0; sx < 2; ++sx) {
                float v = acc[sy][sx][c] + bv;
                if (relu) v = fmaxf(v, 0.f);
                out[(((size_t)n * Cout + co) * H2 + (oy0 + sy)) * W2 + (ox0 + sx)] = v;
            }
        }
    }
}

// ---------------------------------------------------------------------------
// ConvTranspose2d: k=4, stride=2, pad=1.  out[oy] += in[iy]*w[ci][co][ky][kx]
// with oy = 2*iy - 1 + ky  =>  per output exactly 2x2 valid taps.
// Thread computes a same-parity 2x2 output quad (oy0,oy0+2)x(ox0,ox0+2) x 4 co
// so each weight float4 feeds 16 FMAs. Optional fused sigmoid + recon-loss.
// ---------------------------------------------------------------------------
template<int CIN>
__global__ __launch_bounds__(256) void deconv_k4s2(
    const float* __restrict__ in, const float* __restrict__ w,
    const float* __restrict__ bias, float* __restrict__ out,
    int Hin, int Win, int Cout, int quadsPerImg, int totalQuads,
    int relu, int dofinal, const float* __restrict__ xref,
    float* __restrict__ racc)
{
    const int H2 = Hin << 1, W2 = Win << 1;
    const int co0 = blockIdx.y * 4;
    __shared__ float ws[16 * CIN * 4];
    for (int i = threadIdx.x; i < 16 * CIN * 4; i += 256) {
        int c   = i & 3;
        int ci  = (i >> 2) % CIN;
        int tap = i / (4 * CIN);
        float v = 0.f;
        if (co0 + c < Cout)
            v = w[(((size_t)ci * Cout + (co0 + c)) << 4) + tap];  // torch (in,out,kh,kw)
        ws[i] = v;
    }
    __syncthreads();
    int q = blockIdx.x * 256 + threadIdx.x;
    float lsum = 0.f;
    if (q < totalQuads) {
        int n  = q / quadsPerImg;
        int ql = q - n * quadsPerImg;
        int Wq = W2 >> 1;
        int qy = ql / Wq, qx = ql - qy * Wq;
        int oy0 = ((qy >> 1) << 2) + (qy & 1);   // bases 0,1,4,5,8,9,...
        int ox0 = ((qx >> 1) << 2) + (qx & 1);
        int py = (oy0 + 1) & 1, px = (ox0 + 1) & 1;
        int ihc = (oy0 + 1 - py) >> 1;
        int iwc = (ox0 + 1 - px) >> 1;

        float acc[2][2][4];
        #pragma unroll
        for (int sy = 0; sy < 2; ++sy)
            #pragma unroll
            for (int sx = 0; sx < 2; ++sx)
                #pragma unroll
                for (int c = 0; c < 4; ++c) acc[sy][sx][c] = 0.f;

        const float* inn = in + (size_t)n * CIN * Hin * Win;
        for (int ci = 0; ci < CIN; ++ci) {
            const float* ip = inn + (size_t)ci * Hin * Win;
            float xv[3][3];
            #pragma unroll
            for (int r = 0; r < 3; ++r) {
                int iy = ihc - 1 + r;
                bool ry = (iy >= 0) && (iy < Hin);
                #pragma unroll
                for (int cc = 0; cc < 3; ++cc) {
                    int ix = iwc - 1 + cc;
                    xv[r][cc] = (ry && ix >= 0 && ix < Win) ? ip[iy * Win + ix] : 0.f;
                }
            }
            #pragma unroll
            for (int a = 0; a < 2; ++a) {
                #pragma unroll
                for (int b = 0; b < 2; ++b) {
                    int tap = ((py + (a << 1)) << 2) + (px + (b << 1));
                    const float4 wv = *(const float4*)&ws[((tap * CIN + ci) << 2)];
                    #pragma unroll
                    for (int sy = 0; sy < 2; ++sy) {
                        #pragma unroll
                        for (int sx = 0; sx < 2; ++sx) {
                            // output oy0+2sy uses iy = ihc + sy - a
                            float xval = xv[1 + sy - a][1 + sx - b];
                            acc[sy][sx][0] = fmaf(xval, wv.x, acc[sy][sx][0]);
                            acc[sy][sx][1] = fmaf(xval, wv.y, acc[sy][sx][1]);
                            acc[sy][sx][2] = fmaf(xval, wv.z, acc[sy][sx][2]);
                            acc[sy][sx][3] = fmaf(xval, wv.w, acc[sy][sx][3]);
                        }
                    }
                }
            }
        }
        #pragma unroll
        for (int c = 0; c < 4; ++c) {
            int co = co0 + c;
            if (co >= Cout) break;
            float bv = bias[co];
            #pragma unroll
            for (int sy = 0; sy < 2; ++sy) {
                #pragma unroll
                for (int sx = 0; sx < 2; ++sx) {
                    float v = acc[sy][sx][c] + bv;
                    size_t oidx = (((size_t)n * Cout + co) * H2 + (oy0 + (sy << 1))) * W2
                                  + (ox0 + (sx << 1));
                    if (dofinal) {
                        float s = 1.f / (1.f + expf(-v));
                        out[oidx] = s;
                        float d = s - xref[oidx];
                        lsum += d * d;
                    } else {
                        out[oidx] = relu ? fmaxf(v, 0.f) : v;
                    }
                }
            }
        }
    }
    if (dofinal) {
        #pragma unroll
        for (int off = 32; off > 0; off >>= 1)
            lsum += __shfl_down(lsum, off, 64);
        if ((threadIdx.x & 63) == 0) atomicAdd(racc, lsum);
    }
}

// ---------------------------------------------------------------------------
// VQ dot-product GEMM: dot[b][j] = z[b] . emb[j]; M=64, N=4000, K=12544.
// K split 16 ways (784 each) into partial buffer P[split][64][4000].
// ||emb_j||^2 fused into the B-tile load (each emb element read exactly once).
// ---------------------------------------------------------------------------
__global__ __launch_bounds__(256) void vq_gemm(
    const float* __restrict__ z, const float* __restrict__ emb,
    float* __restrict__ P, float* __restrict__ norm_e)
{
    __shared__ float As[64 * 17];
    __shared__ float Bs[64 * 17];
    const int tid = threadIdx.x;
    const int jt = blockIdx.x;
    const int split = blockIdx.y;
    const int lr = tid >> 2;            // 0..63
    const int lk = (tid & 3) << 2;      // 0,4,8,12
    const int jmine = jt * 64 + lr;
    const bool jok = jmine < 4000;
    const float* zp = z + (size_t)lr * 12544 + lk;
    const float* ep = emb + (size_t)(jok ? jmine : 0) * 12544 + lk;
    const int tx = tid & 15, ty = tid >> 4;
    float c[4][4];
    #pragma unroll
    for (int i = 0; i < 4; ++i)
        #pragma unroll
        for (int ii = 0; ii < 4; ++ii) c[i][ii] = 0.f;
    float nsq = 0.f;
    const int kbeg = split * 784;
    for (int k0 = kbeg; k0 < kbeg + 784; k0 += 16) {
        float4 av = *(const float4*)(zp + k0);
        float4 bv = jok ? *(const float4*)(ep + k0) : make_float4(0.f, 0.f, 0.f, 0.f);
        nsq += bv.x * bv.x + bv.y * bv.y + bv.z * bv.z + bv.w * bv.w;
        __syncthreads();
        As[lr * 17 + lk + 0] = av.x; As[lr * 17 + lk + 1] = av.y;
        As[lr * 17 + lk + 2] = av.z; As[lr * 17 + lk + 3] = av.w;
        Bs[lr * 17 + lk + 0] = bv.x; Bs[lr * 17 + lk + 1] = bv.y;
        Bs[lr * 17 + lk + 2] = bv.z; Bs[lr * 17 + lk + 3] = bv.w;
        __syncthreads();
        #pragma unroll
        for (int k = 0; k < 16; ++k) {
            float a0 = As[(ty * 4 + 0) * 17 + k];
            float a1 = As[(ty * 4 + 1) * 17 + k];
            float a2 = As[(ty * 4 + 2) * 17 + k];
            float a3 = As[(ty * 4 + 3) * 17 + k];
            float b0 = Bs[(tx * 4 + 0) * 17 + k];
            float b1 = Bs[(tx * 4 + 1) * 17 + k];
            float b2 = Bs[(tx * 4 + 2) * 17 + k];
            float b3 = Bs[(tx * 4 + 3) * 17 + k];
            c[0][0] = fmaf(a0, b0, c[0][0]); c[0][1] = fmaf(a0, b1, c[0][1]);
            c[0][2] = fmaf(a0, b2, c[0][2]); c[0][3] = fmaf(a0, b3, c[0][3]);
            c[1][0] = fmaf(a1, b0, c[1][0]); c[1][1] = fmaf(a1, b1, c[1][1]);
            c[1][2] = fmaf(a1, b2, c[1][2]); c[1][3] = fmaf(a1, b3, c[1][3]);
            c[2][0] = fmaf(a2, b0, c[2][0]); c[2][1] = fmaf(a2, b1, c[2][1]);
            c[2][2] = fmaf(a2, b2, c[2][2]); c[2][3] = fmaf(a2, b3, c[2][3]);
            c[3][0] = fmaf(a3, b0, c[3][0]); c[3][1] = fmaf(a3, b1, c[3][1]);
            c[3][2] = fmaf(a3, b2, c[3][2]); c[3][3] = fmaf(a3, b3, c[3][3]);
        }
    }
    #pragma unroll
    for (int i = 0; i < 4; ++i) {
        int b = ty * 4 + i;
        #pragma unroll
        for (int ii = 0; ii < 4; ++ii) {
            int j = jt * 64 + tx * 4 + ii;
            if (j < 4000) P[((size_t)split * 64 + b) * 4000 + j] = c[i][ii];
        }
    }
    if (jok) atomicAdd(&norm_e[jmine], nsq);
}

// Argmin over j of (||e_j||^2 - 2*dot[b][j]); first-occurrence tie-break.
__global__ __launch_bounds__(256) void vq_argmin(
    const float* __restrict__ P, const float* __restrict__ norm_e,
    int* __restrict__ idxout)
{
    const int b = blockIdx.x;
    const int tid = threadIdx.x;
    float best = 3.4e38f;
    int bidx = 0x7fffffff;
    for (int j = tid; j < 4000; j += 256) {
        float dot = 0.f;
        #pragma unroll
        for (int s = 0; s < 16; ++s)
            dot += P[((size_t)s * 64 + b) * 4000 + j];
        float d = norm_e[j] - 2.f * dot;
        if (d < best) { best = d; bidx = j; }
    }
    __shared__ float sv[256];
    __shared__ int si[256];
    sv[tid] = best; si[tid] = bidx;
    __syncthreads();
    for (int off = 128; off > 0; off >>= 1) {
        if (tid < off) {
            float v2 = sv[tid + off]; int i2 = si[tid + off];
            if (v2 < sv[tid] || (v2 == sv[tid] && i2 < si[tid])) {
                sv[tid] = v2; si[tid] = i2;
            }
        }
        __syncthreads();
    }
    if (tid == 0) idxout[b] = si[0];
}

// Gather quantized rows + vq-loss partial sum: vq_loss = 1.25*mean((q-z)^2).
__global__ __launch_bounds__(256) void vq_gather(
    const float* __restrict__ emb, const float* __restrict__ z,
    const int* __restrict__ idx, float* __restrict__ Q,
    float* __restrict__ vacc)
{
    const int b = blockIdx.x;
    const int code = idx[b];
    const float* e = emb + (size_t)code * 12544;
    const float* zb = z + (size_t)b * 12544;
    float* qb = Q + (size_t)b * 12544;
    float ls = 0.f;
    for (int d = threadIdx.x; d < 12544; d += 256) {
        float qv = e[d];
        qb[d] = qv;
        float df = qv - zb[d];
        ls += df * df;
    }
    #pragma unroll
    for (int off = 32; off > 0; off >>= 1)
        ls += __shfl_down(ls, off, 64);
    if ((threadIdx.x & 63) == 0) atomicAdd(vacc, ls);
}

__global__ void vq_finalize(const float* __restrict__ acc, float* __restrict__ tail)
{
    float recon = acc[1] * (1.f / 9633792.f);
    float vq    = 1.25f * acc[0] * (1.f / 802816.f);
    tail[0] = recon + vq;   // loss
    tail[1] = recon;        // recon_loss
    tail[2] = vq;           // vq_loss
}

// ---------------------------------------------------------------------------
extern "C" void kernel_launch(void* const* d_in, const int* in_sizes, int n_in,
                              void* d_out, int out_size, void* d_ws, size_t ws_size,
                              hipStream_t stream)
{
    const float* x   = (const float*)d_in[0];
    const float* ew1 = (const float*)d_in[1];
    const float* eb1 = (const float*)d_in[2];
    const float* ew2 = (const float*)d_in[3];
    const float* eb2 = (const float*)d_in[4];
    const float* ew3 = (const float*)d_in[5];
    const float* eb3 = (const float*)d_in[6];
    const float* ew4 = (const float*)d_in[7];
    const float* eb4 = (const float*)d_in[8];
    const float* emb = (const float*)d_in[9];
    const float* dw1 = (const float*)d_in[10];
    const float* db1 = (const float*)d_in[11];
    const float* dw2 = (const float*)d_in[12];
    const float* db2 = (const float*)d_in[13];
    const float* dw3 = (const float*)d_in[14];
    const float* db3 = (const float*)d_in[15];
    const float* dw4 = (const float*)d_in[16];
    const float* db4 = (const float*)d_in[17];
    float* out = (float*)d_out;

    // workspace layout (floats), with reuse: A(h1,d3) B(h2,d2) C(h3,d1; P aliases C)
    float* Wf  = (float*)d_ws;
    float* A   = Wf;                    // 25,690,112
    float* Bb  = A + 25690112;          // 12,845,056
    float* C   = Bb + 12845056;         //  6,422,528
    float* P   = C;                     //  4,096,000 (aliases C; C free at that point)
    float* D   = C + 6422528;           //    802,816  (z)
    float* E   = D + 802816;            //    802,816  (quantized)
    float* nrm = E + 802816;            //      4,000
    float* acc = nrm + 4000;            // [0]=vq sum, [1]=recon sum
    int*   idx = (int*)(acc + 2);       //         64

    hipMemsetAsync(nrm, 0, 4002 * sizeof(float), stream);

    // ---- Encoder ----
    conv_k4s2<3  ><<<dim3(784, 8),  256, 0, stream>>>(x,  ew1, eb1, A,  224, 224, 32,  3136, 200704, 1);
    conv_k4s2<32 ><<<dim3(196, 16), 256, 0, stream>>>(A,  ew2, eb2, Bb, 112, 112, 64,  784,  50176,  1);
    conv_k4s2<64 ><<<dim3(49, 32),  256, 0, stream>>>(Bb, ew3, eb3, C,  56,  56,  128, 196,  12544,  1);
    conv_k4s2<128><<<dim3(13, 16),  256, 0, stream>>>(C,  ew4, eb4, D,  28,  28,  64,  49,   3136,   0);

    // ---- Vector quantization ----
    vq_gemm   <<<dim3(63, 16), 256, 0, stream>>>(D, emb, P, nrm);
    vq_argmin <<<dim3(64),     256, 0, stream>>>(P, nrm, idx);
    vq_gather <<<dim3(64),     256, 0, stream>>>(emb, D, idx, E, acc);

    // ---- Decoder ----
    deconv_k4s2<64 ><<<dim3(49, 32),  256, 0, stream>>>(E,  dw1, db1, C,   14,  14,  128, 196,  12544,  1, 0, nullptr, nullptr);
    deconv_k4s2<128><<<dim3(196, 16), 256, 0, stream>>>(C,  dw2, db2, Bb,  28,  28,  64,  784,  50176,  1, 0, nullptr, nullptr);
    deconv_k4s2<64 ><<<dim3(784, 8),  256, 0, stream>>>(Bb, dw3, db3, A,   56,  56,  32,  3136, 200704, 1, 0, nullptr, nullptr);
    deconv_k4s2<32 ><<<dim3(3136, 1), 256, 0, stream>>>(A,  dw4, db4, out, 112, 112, 3,   12544, 802816, 0, 1, x, acc + 1);

    vq_finalize<<<1, 1, 0, stream>>>(acc, out + 9633792);
}

// Round 2
// 2191.400 us; speedup vs baseline: 1.5832x; 1.5832x over previous
//
#include <hip/hip_runtime.h>
#include <math.h>

// ===========================================================================
// Tiled encoder conv: k=4, s=2, p=1. Block = full-width tile of TOH output
// rows x ALL Cout. Input tile + weight chunk staged in LDS, ci-chunked.
// Thread = PX consecutive ox x CO_T channels (register blocked).
// ===========================================================================
template<int CIN, int CICH, int COUT, int CO_T, int HIN, int WIN, int TOH, int PX, int RELU>
__global__ __launch_bounds__(256) void conv_t(
    const float* __restrict__ in, const float* __restrict__ w,
    const float* __restrict__ bias, float* __restrict__ out)
{
    constexpr int H2 = HIN / 2, W2 = WIN / 2;
    constexpr int ROWS = 2 * TOH + 2, COLS = WIN + 2;
    constexpr int GW = W2 / PX;
    constexpr int COGRP = COUT / CO_T;
    constexpr int UNITS = TOH * GW * COGRP;
    constexpr int TILES = H2 / TOH;
    constexpr int TSZ = CICH * ROWS * COLS;
    constexpr int WSZ = CICH * 16 * COUT;
    __shared__ float tileS[TSZ];
    __shared__ float wS[WSZ];

    const int tid = threadIdx.x;
    const int n = blockIdx.x / TILES;
    const int t0 = (blockIdx.x % TILES) * TOH;
    const int iy_base = 2 * t0 - 1;
    const bool active = tid < UNITS;
    const int cog = tid / (TOH * GW);
    const int rem = tid % (TOH * GW);
    const int ty = rem / GW, gx = rem % GW;
    const int oy = t0 + ty, ox0 = gx * PX, co0 = cog * CO_T;

    float acc[PX][CO_T];
    #pragma unroll
    for (int p = 0; p < PX; ++p)
        #pragma unroll
        for (int c = 0; c < CO_T; ++c) acc[p][c] = 0.f;

    for (int ci0 = 0; ci0 < CIN; ci0 += CICH) {
        // ---- stage input tile (zero-padded halo) ----
        for (int i = tid; i < TSZ; i += 256) {
            int cil = i / (ROWS * COLS), r2 = i % (ROWS * COLS);
            int r = r2 / COLS, c = r2 % COLS;
            int iy = iy_base + r, ix = c - 1;
            float v = 0.f;
            if (iy >= 0 && iy < HIN && ix >= 0 && ix < WIN)
                v = in[(((size_t)n * CIN + ci0 + cil) * HIN + iy) * WIN + ix];
            tileS[i] = v;
        }
        // ---- stage weights: wS[(cil*16+tap)*COUT + co] ; OIHW source ----
        for (int i = tid; i < WSZ; i += 256) {
            int co = i / (CICH * 16), r = i % (CICH * 16);
            wS[r * COUT + co] = w[((size_t)co * CIN + ci0) * 16 + r];
        }
        __syncthreads();
        if (active) {
            #pragma unroll 1
            for (int cil = 0; cil < CICH; ++cil) {
                const float* tp = &tileS[cil * ROWS * COLS];
                const float* wp = &wS[cil * 16 * COUT];
                #pragma unroll
                for (int ky = 0; ky < 4; ++ky) {
                    const int r = 2 * ty + ky;
                    float xrow[2 * PX + 2];
                    #pragma unroll
                    for (int m = 0; m < 2 * PX + 2; ++m)
                        xrow[m] = tp[r * COLS + 2 * ox0 + m];
                    #pragma unroll
                    for (int kx = 0; kx < 4; ++kx) {
                        const float* wq = &wp[(ky * 4 + kx) * COUT + co0];
                        #pragma unroll
                        for (int cq = 0; cq < CO_T / 4; ++cq) {
                            const float4 wv = *(const float4*)&wq[cq * 4];
                            #pragma unroll
                            for (int p = 0; p < PX; ++p) {
                                const float xv = xrow[2 * p + kx];
                                acc[p][cq * 4 + 0] = fmaf(xv, wv.x, acc[p][cq * 4 + 0]);
                                acc[p][cq * 4 + 1] = fmaf(xv, wv.y, acc[p][cq * 4 + 1]);
                                acc[p][cq * 4 + 2] = fmaf(xv, wv.z, acc[p][cq * 4 + 2]);
                                acc[p][cq * 4 + 3] = fmaf(xv, wv.w, acc[p][cq * 4 + 3]);
                            }
                        }
                    }
                }
            }
        }
        __syncthreads();
    }
    if (active) {
        #pragma unroll
        for (int c = 0; c < CO_T; ++c) {
            const int co = co0 + c;
            const float bv = bias[co];
            #pragma unroll
            for (int p = 0; p < PX; ++p) {
                float v = acc[p][c] + bv;
                if (RELU) v = fmaxf(v, 0.f);
                out[(((size_t)n * COUT + co) * H2 + oy) * W2 + (ox0 + p)] = v;
            }
        }
    }
}

// ===========================================================================
// Tiled ConvTranspose2d: k=4, s=2, p=1. out[oy,ox] has exactly 2x2 valid taps
// (ky in {py,py+2}, kx in {px,px+2}). Block = full-width TOH output rows x all
// Cout; input tile + weight chunk in LDS; thread = PX ox x CO_T co.
// Optional fused sigmoid + recon-loss accumulation.
// ===========================================================================
template<int CIN, int CICH, int COUT, int CO_T, int HIN, int WIN, int TOH, int PX,
         int RELU, int DOFINAL>
__global__ __launch_bounds__(256) void deconv_t(
    const float* __restrict__ in, const float* __restrict__ w,
    const float* __restrict__ bias, float* __restrict__ out,
    const float* __restrict__ xref, float* __restrict__ racc)
{
    constexpr int H2 = HIN * 2, W2 = WIN * 2;
    constexpr int IROWS = TOH / 2 + 2, COLS = WIN + 2;
    constexpr int CO_PAD = (COUT + 3) & ~3;
    constexpr int GW = W2 / PX;
    constexpr int COGRP = (COUT + CO_T - 1) / CO_T;
    constexpr int UNITS = TOH * GW * COGRP;
    constexpr int TILES = H2 / TOH;
    constexpr int TSZ = CICH * IROWS * COLS;
    constexpr int WSZ = CICH * 16 * CO_PAD;
    __shared__ float tileS[TSZ];
    __shared__ float wS[WSZ];

    const int tid = threadIdx.x;
    const int n = blockIdx.x / TILES;
    const int t0 = (blockIdx.x % TILES) * TOH;
    const int iy_lo = (t0 >> 1) - 1;
    const bool active = tid < UNITS;
    const int cog = tid / (TOH * GW);
    const int rem = tid % (TOH * GW);
    const int ty = rem / GW, gx = rem % GW;
    const int oy = t0 + ty, ox0 = gx * PX, co0 = cog * CO_T;
    const int py = (oy + 1) & 1;
    const int iy_hi = (oy + 1 - py) >> 1;
    const int r1 = iy_hi - iy_lo;       // row for ky=py; ky=py+2 uses r1-1
    const int c0 = ox0 >> 1;

    float acc[PX][CO_T];
    #pragma unroll
    for (int p = 0; p < PX; ++p)
        #pragma unroll
        for (int c = 0; c < CO_T; ++c) acc[p][c] = 0.f;

    for (int ci0 = 0; ci0 < CIN; ci0 += CICH) {
        for (int i = tid; i < TSZ; i += 256) {
            int cil = i / (IROWS * COLS), r2 = i % (IROWS * COLS);
            int r = r2 / COLS, c = r2 % COLS;
            int iy = iy_lo + r, ix = c - 1;
            float v = 0.f;
            if (iy >= 0 && iy < HIN && ix >= 0 && ix < WIN)
                v = in[(((size_t)n * CIN + ci0 + cil) * HIN + iy) * WIN + ix];
            tileS[i] = v;
        }
        if (CO_PAD != COUT) {
            for (int i = tid; i < CICH * 16; i += 256)
                #pragma unroll
                for (int c = COUT; c < CO_PAD; ++c) wS[i * CO_PAD + c] = 0.f;
        }
        // torch layout (in, out, kh, kw): chunk is fully contiguous
        for (int i = tid; i < CICH * COUT * 16; i += 256) {
            int cil = i / (COUT * 16), r2 = i % (COUT * 16);
            int co = r2 / 16, tap = r2 % 16;
            wS[(cil * 16 + tap) * CO_PAD + co] = w[(size_t)ci0 * COUT * 16 + i];
        }
        __syncthreads();
        if (active) {
            #pragma unroll 1
            for (int cil = 0; cil < CICH; ++cil) {
                const float* tp = &tileS[cil * IROWS * COLS];
                const float* wp = &wS[cil * 16 * CO_PAD];
                float xr[2][PX / 2 + 2];
                #pragma unroll
                for (int k2 = 0; k2 < 2; ++k2)
                    #pragma unroll
                    for (int j = 0; j < PX / 2 + 2; ++j)
                        xr[k2][j] = tp[(r1 - k2) * COLS + c0 + j];
                #pragma unroll
                for (int k2 = 0; k2 < 2; ++k2) {
                    #pragma unroll
                    for (int kx = 0; kx < 4; ++kx) {
                        const int tap = (py + 2 * k2) * 4 + kx;
                        const int kx2 = kx >> 1;
                        #pragma unroll
                        for (int cq = 0; cq < CO_T / 4; ++cq) {
                            const float4 wv = *(const float4*)&wp[tap * CO_PAD + co0 + cq * 4];
                            #pragma unroll
                            for (int pp = 0; pp < PX / 2; ++pp) {
                                const int p = 2 * pp + ((kx & 1) ^ 1);
                                const int j = ((p + (p & 1)) >> 1) + 1 - kx2;
                                const float xv = xr[k2][j];
                                acc[p][cq * 4 + 0] = fmaf(xv, wv.x, acc[p][cq * 4 + 0]);
                                acc[p][cq * 4 + 1] = fmaf(xv, wv.y, acc[p][cq * 4 + 1]);
                                acc[p][cq * 4 + 2] = fmaf(xv, wv.z, acc[p][cq * 4 + 2]);
                                acc[p][cq * 4 + 3] = fmaf(xv, wv.w, acc[p][cq * 4 + 3]);
                            }
                        }
                    }
                }
            }
        }
        __syncthreads();
    }

    float lsum = 0.f;
    if (active) {
        #pragma unroll
        for (int c = 0; c < CO_T; ++c) {
            const int co = co0 + c;
            if (co >= COUT) break;
            const float bv = bias[co];
            #pragma unroll
            for (int p = 0; p < PX; ++p) {
                float v = acc[p][c] + bv;
                size_t oidx = (((size_t)n * COUT + co) * H2 + oy) * W2 + (ox0 + p);
                if (DOFINAL) {
                    float s = 1.f / (1.f + expf(-v));
                    out[oidx] = s;
                    float d = s - xref[oidx];
                    lsum += d * d;
                } else {
                    out[oidx] = RELU ? fmaxf(v, 0.f) : v;
                }
            }
        }
    }
    if (DOFINAL) {
        #pragma unroll
        for (int off = 32; off > 0; off >>= 1)
            lsum += __shfl_down(lsum, off, 64);
        if ((threadIdx.x & 63) == 0) atomicAdd(racc, lsum);
    }
}

// ---------------------------------------------------------------------------
// VQ dot-product GEMM: dot[b][j] = z[b] . emb[j]; M=64, N=4000, K=12544.
// ---------------------------------------------------------------------------
__global__ __launch_bounds__(256) void vq_gemm(
    const float* __restrict__ z, const float* __restrict__ emb,
    float* __restrict__ P, float* __restrict__ norm_e)
{
    __shared__ float As[64 * 17];
    __shared__ float Bs[64 * 17];
    const int tid = threadIdx.x;
    const int jt = blockIdx.x;
    const int split = blockIdx.y;
    const int lr = tid >> 2;
    const int lk = (tid & 3) << 2;
    const int jmine = jt * 64 + lr;
    const bool jok = jmine < 4000;
    const float* zp = z + (size_t)lr * 12544 + lk;
    const float* ep = emb + (size_t)(jok ? jmine : 0) * 12544 + lk;
    const int tx = tid & 15, ty = tid >> 4;
    float c[4][4];
    #pragma unroll
    for (int i = 0; i < 4; ++i)
        #pragma unroll
        for (int ii = 0; ii < 4; ++ii) c[i][ii] = 0.f;
    float nsq = 0.f;
    const int kbeg = split * 784;
    for (int k0 = kbeg; k0 < kbeg + 784; k0 += 16) {
        float4 av = *(const float4*)(zp + k0);
        float4 bv = jok ? *(const float4*)(ep + k0) : make_float4(0.f, 0.f, 0.f, 0.f);
        nsq += bv.x * bv.x + bv.y * bv.y + bv.z * bv.z + bv.w * bv.w;
        __syncthreads();
        As[lr * 17 + lk + 0] = av.x; As[lr * 17 + lk + 1] = av.y;
        As[lr * 17 + lk + 2] = av.z; As[lr * 17 + lk + 3] = av.w;
        Bs[lr * 17 + lk + 0] = bv.x; Bs[lr * 17 + lk + 1] = bv.y;
        Bs[lr * 17 + lk + 2] = bv.z; Bs[lr * 17 + lk + 3] = bv.w;
        __syncthreads();
        #pragma unroll
        for (int k = 0; k < 16; ++k) {
            float a0 = As[(ty * 4 + 0) * 17 + k];
            float a1 = As[(ty * 4 + 1) * 17 + k];
            float a2 = As[(ty * 4 + 2) * 17 + k];
            float a3 = As[(ty * 4 + 3) * 17 + k];
            float b0 = Bs[(tx * 4 + 0) * 17 + k];
            float b1 = Bs[(tx * 4 + 1) * 17 + k];
            float b2 = Bs[(tx * 4 + 2) * 17 + k];
            float b3 = Bs[(tx * 4 + 3) * 17 + k];
            c[0][0] = fmaf(a0, b0, c[0][0]); c[0][1] = fmaf(a0, b1, c[0][1]);
            c[0][2] = fmaf(a0, b2, c[0][2]); c[0][3] = fmaf(a0, b3, c[0][3]);
            c[1][0] = fmaf(a1, b0, c[1][0]); c[1][1] = fmaf(a1, b1, c[1][1]);
            c[1][2] = fmaf(a1, b2, c[1][2]); c[1][3] = fmaf(a1, b3, c[1][3]);
            c[2][0] = fmaf(a2, b0, c[2][0]); c[2][1] = fmaf(a2, b1, c[2][1]);
            c[2][2] = fmaf(a2, b2, c[2][2]); c[2][3] = fmaf(a2, b3, c[2][3]);
            c[3][0] = fmaf(a3, b0, c[3][0]); c[3][1] = fmaf(a3, b1, c[3][1]);
            c[3][2] = fmaf(a3, b2, c[3][2]); c[3][3] = fmaf(a3, b3, c[3][3]);
        }
    }
    #pragma unroll
    for (int i = 0; i < 4; ++i) {
        int b = ty * 4 + i;
        #pragma unroll
        for (int ii = 0; ii < 4; ++ii) {
            int j = jt * 64 + tx * 4 + ii;
            if (j < 4000) P[((size_t)split * 64 + b) * 4000 + j] = c[i][ii];
        }
    }
    if (jok) atomicAdd(&norm_e[jmine], nsq);
}

__global__ __launch_bounds__(256) void vq_argmin(
    const float* __restrict__ P, const float* __restrict__ norm_e,
    int* __restrict__ idxout)
{
    const int b = blockIdx.x;
    const int tid = threadIdx.x;
    float best = 3.4e38f;
    int bidx = 0x7fffffff;
    for (int j = tid; j < 4000; j += 256) {
        float dot = 0.f;
        #pragma unroll
        for (int s = 0; s < 16; ++s)
            dot += P[((size_t)s * 64 + b) * 4000 + j];
        float d = norm_e[j] - 2.f * dot;
        if (d < best) { best = d; bidx = j; }
    }
    __shared__ float sv[256];
    __shared__ int si[256];
    sv[tid] = best; si[tid] = bidx;
    __syncthreads();
    for (int off = 128; off > 0; off >>= 1) {
        if (tid < off) {
            float v2 = sv[tid + off]; int i2 = si[tid + off];
            if (v2 < sv[tid] || (v2 == sv[tid] && i2 < si[tid])) {
                sv[tid] = v2; si[tid] = i2;
            }
        }
        __syncthreads();
    }
    if (tid == 0) idxout[b] = si[0];
}

__global__ __launch_bounds__(256) void vq_gather(
    const float* __restrict__ emb, const float* __restrict__ z,
    const int* __restrict__ idx, float* __restrict__ Q,
    float* __restrict__ vacc)
{
    const int b = blockIdx.x;
    const int code = idx[b];
    const float* e = emb + (size_t)code * 12544;
    const float* zb = z + (size_t)b * 12544;
    float* qb = Q + (size_t)b * 12544;
    float ls = 0.f;
    for (int d = threadIdx.x; d < 12544; d += 256) {
        float qv = e[d];
        qb[d] = qv;
        float df = qv - zb[d];
        ls += df * df;
    }
    #pragma unroll
    for (int off = 32; off > 0; off >>= 1)
        ls += __shfl_down(ls, off, 64);
    if ((threadIdx.x & 63) == 0) atomicAdd(vacc, ls);
}

__global__ void vq_finalize(const float* __restrict__ acc, float* __restrict__ tail)
{
    float recon = acc[1] * (1.f / 9633792.f);
    float vq    = 1.25f * acc[0] * (1.f / 802816.f);
    tail[0] = recon + vq;
    tail[1] = recon;
    tail[2] = vq;
}

// ---------------------------------------------------------------------------
extern "C" void kernel_launch(void* const* d_in, const int* in_sizes, int n_in,
                              void* d_out, int out_size, void* d_ws, size_t ws_size,
                              hipStream_t stream)
{
    const float* x   = (const float*)d_in[0];
    const float* ew1 = (const float*)d_in[1];
    const float* eb1 = (const float*)d_in[2];
    const float* ew2 = (const float*)d_in[3];
    const float* eb2 = (const float*)d_in[4];
    const float* ew3 = (const float*)d_in[5];
    const float* eb3 = (const float*)d_in[6];
    const float* ew4 = (const float*)d_in[7];
    const float* eb4 = (const float*)d_in[8];
    const float* emb = (const float*)d_in[9];
    const float* dw1 = (const float*)d_in[10];
    const float* db1 = (const float*)d_in[11];
    const float* dw2 = (const float*)d_in[12];
    const float* db2 = (const float*)d_in[13];
    const float* dw3 = (const float*)d_in[14];
    const float* db3 = (const float*)d_in[15];
    const float* dw4 = (const float*)d_in[16];
    const float* db4 = (const float*)d_in[17];
    float* out = (float*)d_out;

    float* Wf  = (float*)d_ws;
    float* A   = Wf;                    // 25,690,112 (h1 / d3)
    float* Bb  = A + 25690112;          // 12,845,056 (h2 / d2)
    float* C   = Bb + 12845056;         //  6,422,528 (h3 / d1)
    float* P   = C;                     //  4,096,000 (aliases C)
    float* D   = C + 6422528;           //    802,816 (z)
    float* E   = D + 802816;            //    802,816 (quantized)
    float* nrm = E + 802816;            //      4,000
    float* acc = nrm + 4000;            // [0]=vq sum, [1]=recon sum
    int*   idx = (int*)(acc + 2);

    hipMemsetAsync(nrm, 0, 4002 * sizeof(float), stream);

    // ---- Encoder ----  <CIN,CICH,COUT,CO_T,HIN,WIN,TOH,PX,RELU>
    conv_t<3,  3, 32, 16, 224, 224, 4, 4, 1><<<1792, 256, 0, stream>>>(x,  ew1, eb1, A);
    conv_t<32, 4, 64, 16, 112, 112, 4, 4, 1><<<896,  256, 0, stream>>>(A,  ew2, eb2, Bb);
    conv_t<64, 4, 128,16, 56,  56,  4, 4, 1><<<448,  256, 0, stream>>>(Bb, ew3, eb3, C);
    conv_t<128,8, 64, 16, 28,  28,  7, 2, 0><<<128,  256, 0, stream>>>(C,  ew4, eb4, D);

    // ---- Vector quantization ----
    vq_gemm   <<<dim3(63, 16), 256, 0, stream>>>(D, emb, P, nrm);
    vq_argmin <<<dim3(64),     256, 0, stream>>>(P, nrm, idx);
    vq_gather <<<dim3(64),     256, 0, stream>>>(emb, D, idx, E, acc);

    // ---- Decoder ----  <CIN,CICH,COUT,CO_T,HIN,WIN,TOH,PX,RELU,DOFINAL>
    deconv_t<64, 4, 128,16, 14,  14,  4, 4, 1, 0><<<448,  256, 0, stream>>>(E,  dw1, db1, C,   nullptr, nullptr);
    deconv_t<128,8, 64, 8,  28,  28,  4, 8, 1, 0><<<896,  256, 0, stream>>>(C,  dw2, db2, Bb,  nullptr, nullptr);
    deconv_t<64, 8, 32, 8,  56,  56,  4, 8, 1, 0><<<1792, 256, 0, stream>>>(Bb, dw3, db3, A,   nullptr, nullptr);
    deconv_t<32, 8, 3,  4,  112, 112, 8, 8, 0, 1><<<1792, 256, 0, stream>>>(A,  dw4, db4, out, x, acc + 1);

    vq_finalize<<<1, 1, 0, stream>>>(acc, out + 9633792);
}

// Round 4
// 1359.013 us; speedup vs baseline: 2.5528x; 1.6125x over previous
//
#include <hip/hip_runtime.h>
#include <math.h>

typedef unsigned short u16;
typedef unsigned int u32;
typedef __attribute__((ext_vector_type(8))) short short8;
typedef __attribute__((ext_vector_type(4))) float f32x4;

__device__ __forceinline__ u16 f2bf(float f) {
    u32 u = __float_as_uint(f);
    u = u + 0x7fffu + ((u >> 16) & 1u);
    return (u16)(u >> 16);
}
__device__ __forceinline__ float bf2f(u16 h) { return __uint_as_float(((u32)h) << 16); }

__device__ __forceinline__ f32x4 mfma16(short8 a, short8 b, f32x4 c) {
    return __builtin_amdgcn_mfma_f32_16x16x32_bf16(a, b, c, 0, 0, 0);
}

__device__ __forceinline__ uint4 pack8(float4 a, float4 b) {
    uint4 r;
    r.x = (u32)f2bf(a.x) | ((u32)f2bf(a.y) << 16);
    r.y = (u32)f2bf(a.z) | ((u32)f2bf(a.w) << 16);
    r.z = (u32)f2bf(b.x) | ((u32)f2bf(b.y) << 16);
    r.w = (u32)f2bf(b.z) | ((u32)f2bf(b.w) << 16);
    return r;
}

// ===========================================================================
// Weight prep: fp32 -> bf16, interleaved per-chunk layouts (run once/launch).
// ===========================================================================
// conv weights OIHW -> [ch][tap][co][ci8]
__global__ __launch_bounds__(256) void prep_conv_w(
    const float* __restrict__ w, u16* __restrict__ o, int CIN, int COUT)
{
    int i = blockIdx.x * 256 + threadIdx.x;
    int tot = CIN * 16 * COUT;
    if (i >= tot) return;
    int j = i & 7; int r = i >> 3;
    int co = r % COUT; int r2 = r / COUT;
    int tap = r2 & 15; int ch = r2 >> 4;
    int ci = ch * 8 + j;
    o[i] = f2bf(w[((size_t)co * CIN + ci) * 16 + tap]);
}
// deconv (torch in,out,kh,kw) -> [ch][py*2+px][q=ta*2+tb][co][ci8]
__global__ __launch_bounds__(256) void prep_deconv_w(
    const float* __restrict__ w, u16* __restrict__ o, int CIN, int COUT, int COPAD)
{
    int i = blockIdx.x * 256 + threadIdx.x;
    int tot = CIN * 16 * COPAD;
    if (i >= tot) return;
    int j = i & 7; int r = i >> 3;
    int co = r % COPAD; int r2 = r / COPAD;
    int t16 = r2 & 15; int ch = r2 >> 4;
    int py = t16 >> 3, px = (t16 >> 2) & 1, qq = t16 & 3;
    int ta = qq >> 1, tb = qq & 1;
    int ky = py + 2 * ta, kx = px + 2 * tb;
    int ci = ch * 8 + j;
    o[i] = (co < COUT) ? f2bf(w[(((size_t)ci * COUT + co) * 16) + ky * 4 + kx]) : (u16)0;
}
// conv1 weights -> [h][ky][co][kx*2+cp]  (ci = 2h+cp, ci=3 padded); 2048 entries
__global__ __launch_bounds__(256) void prep_conv1_w(
    const float* __restrict__ w, u16* __restrict__ o)
{
    int i = blockIdx.x * 256 + threadIdx.x;
    if (i >= 2048) return;                 // FIX: was 512 (dropped 3/4 of taps)
    int j = i & 7; int kx = j >> 1, cp = j & 1;
    int r = i >> 3;
    int co = r & 31; int r2 = r >> 5;
    int ky = r2 & 3; int h = r2 >> 2;
    int ci = 2 * h + cp;
    o[i] = (ci < 3) ? f2bf(w[((co * 3 + ci) * 16) + ky * 4 + kx]) : (u16)0;
}

// ===========================================================================
// Generic conv (k=4,s=2,p=1) implicit-GEMM MFMA kernel.
// in: bf16 NC8HW8. A-frag: quad = kx, j = ci-in-chunk. K-loop: chunks x ky.
// ===========================================================================
template<int CIN, int COUT, int COTILE, int H2, int W2, int NSEG, int MB,
         int MBW, int NWF, int RELU, int STOREZ>
__global__ __launch_bounds__(256) void conv_mfma(
    const u16* __restrict__ in, const u16* __restrict__ wcvt,
    const float* __restrict__ bias, u16* __restrict__ outp,
    float* __restrict__ z32)
{
    constexpr int CHUNKS = CIN / 8, CGI = CIN / 8, CGO = COUT / 8;
    constexpr int HIN = H2 * 2, WIN = W2 * 2, SLOTW = 35;
    constexpr int NF = COTILE / 16, WM = MB / MBW, WN = NF / NWF;
    static_assert(WM * WN == 4, "wave layout");
    constexpr int TBu = MB * 4 * SLOTW, WBu = 16 * COTILE;
    constexpr int EBu = (MB * 16 * COTILE * 2 + 15) / 16;
    constexpr int SM = (TBu + WBu) > EBu ? (TBu + WBu) : EBu;
    __shared__ uint4 smem[SM];
    uint4* T = smem; uint4* wS = smem + TBu;
    u16* E = (u16*)smem;

    const int tid = threadIdx.x, wid = tid >> 6, lane = tid & 63;
    const int q = lane >> 4, lm = lane & 15;
    const int wm = wid / WN, wn = wid % WN;
    const int cobase = blockIdx.y * COTILE;
    const int mbase = blockIdx.x * MB;

    f32x4 acc[MBW][NWF];
    #pragma unroll
    for (int a = 0; a < MBW; ++a)
        #pragma unroll
        for (int b = 0; b < NWF; ++b) {
            acc[a][b][0] = 0.f; acc[a][b][1] = 0.f;
            acc[a][b][2] = 0.f; acc[a][b][3] = 0.f;
        }

    for (int ch = 0; ch < CHUNKS; ++ch) {
        __syncthreads();
        for (int i = tid; i < TBu; i += 256) {
            int mb = i / (4 * SLOTW), r2 = i % (4 * SLOTW);
            int r = r2 / SLOTW, s = r2 % SLOTW;
            int mbg = mbase + mb;
            int n = mbg / (H2 * NSEG), rr = mbg % (H2 * NSEG);
            int oy = rr / NSEG, ox0 = (rr % NSEG) << 4;
            int iy = 2 * oy - 1 + r, ix = 2 * ox0 - 1 + s;
            uint4 v = {0u, 0u, 0u, 0u};
            if ((unsigned)iy < (unsigned)HIN && (unsigned)ix < (unsigned)WIN)
                v = *(const uint4*)(in + (size_t)(((n * CGI + ch) * HIN + iy) * WIN + ix) * 8);
            T[i] = v;
        }
        for (int i = tid; i < WBu; i += 256) {
            int tap = i / COTILE, co = i % COTILE;
            wS[i] = *(const uint4*)(wcvt + (size_t)((ch * 16 + tap) * COUT + cobase + co) * 8);
        }
        __syncthreads();
        #pragma unroll
        for (int ky = 0; ky < 4; ++ky) {
            short8 Af[MBW]; short8 Bf[NWF];
            #pragma unroll
            for (int im = 0; im < MBW; ++im) {
                int mb = wm * MBW + im;
                Af[im] = *(const short8*)(T + (mb * 4 + ky) * SLOTW + 2 * lm + q);
            }
            #pragma unroll
            for (int inf = 0; inf < NWF; ++inf)
                Bf[inf] = *(const short8*)(wS + (ky * 4 + q) * COTILE + wn * NWF * 16 + inf * 16 + lm);
            #pragma unroll
            for (int im = 0; im < MBW; ++im)
                #pragma unroll
                for (int inf = 0; inf < NWF; ++inf)
                    acc[im][inf] = mfma16(Af[im], Bf[inf], acc[im][inf]);
        }
    }
    __syncthreads();
    #pragma unroll
    for (int inf = 0; inf < NWF; ++inf) {
        int col = wn * NWF * 16 + inf * 16 + lm;
        float bv = bias[cobase + col];
        #pragma unroll
        for (int im = 0; im < MBW; ++im) {
            int pixb = (wm * MBW + im) * 16 + q * 4;
            #pragma unroll
            for (int r = 0; r < 4; ++r) {
                float v = acc[im][inf][r] + bv;
                if (RELU) v = fmaxf(v, 0.f);
                E[(pixb + r) * COTILE + col] = f2bf(v);
            }
        }
    }
    __syncthreads();
    for (int i = tid; i < MB * 16 * (COTILE / 8); i += 256) {
        int pix = i / (COTILE / 8), cg = i % (COTILE / 8);
        int mb = pix >> 4, m = pix & 15;
        int mbg = mbase + mb;
        int n = mbg / (H2 * NSEG), rr = mbg % (H2 * NSEG);
        int oy = rr / NSEG, ox0 = (rr % NSEG) << 4;
        int ox = ox0 + m;
        if (ox < W2)
            *(uint4*)(outp + (size_t)(((n * CGO + cobase / 8 + cg) * H2 + oy) * W2 + ox) * 8) =
                *(uint4*)(E + pix * COTILE + cg * 8);
    }
    if (STOREZ) {
        for (int i = tid; i < MB * 16 * COTILE; i += 256) {
            int pix = i / COTILE, co = i % COTILE;
            int mb = pix >> 4, m = pix & 15;
            int mbg = mbase + mb;
            int n = mbg / (H2 * NSEG), rr = mbg % (H2 * NSEG);
            int oy = rr / NSEG, ox0 = (rr % NSEG) << 4;
            int ox = ox0 + m;
            if (ox < W2)
                z32[(size_t)((n * COUT + cobase + co) * H2 + oy) * W2 + ox] =
                    bf2f(E[pix * COTILE + co]);
        }
    }
}

// ===========================================================================
// conv1 (CIN=3) special: quad = ky, j = kx*2+cp (ci=2h+cp), 2 halves h.
// ===========================================================================
__global__ __launch_bounds__(256) void conv1_mfma(
    const float* __restrict__ x, const u16* __restrict__ w1c,
    const float* __restrict__ bias, u16* __restrict__ outp)
{
    constexpr int MB = 16, MBW = 4, NWF = 2, COTILE = 32, W2 = 112, H2 = 112, NSEG = 7;
    constexpr int TBu = MB * 2 * 64, WBu = 256;
    __shared__ uint4 smem[TBu + WBu];  // 36 KB; E (16 KB) aliases
    uint4* T1 = smem; uint4* w1S = smem + TBu;
    u16* E = (u16*)smem;

    const int tid = threadIdx.x, wid = tid >> 6, lane = tid & 63;
    const int q = lane >> 4, lm = lane & 15;
    const int wm = wid;  // WM=4, WN=1
    const int mbase = blockIdx.x * MB;

    f32x4 acc[MBW][NWF];
    #pragma unroll
    for (int a = 0; a < MBW; ++a)
        #pragma unroll
        for (int b = 0; b < NWF; ++b) {
            acc[a][b][0] = 0.f; acc[a][b][1] = 0.f;
            acc[a][b][2] = 0.f; acc[a][b][3] = 0.f;
        }

    // stage input (single chunk covers all of CIN=3)
    for (int i = tid; i < TBu; i += 256) {
        int mb = i >> 7; int r = i & 127;
        int h = r >> 6; int r2 = r & 63;
        int ky = r2 >> 4; int m = r2 & 15;
        int mbg = mbase + mb;
        int n = mbg / (H2 * NSEG), rr = mbg % (H2 * NSEG);
        int oy = rr / NSEG, ox0 = (rr % NSEG) << 4;
        int iy = 2 * oy - 1 + ky;
        int ixb = 2 * (ox0 + m) - 1;
        u32 u[4];
        #pragma unroll
        for (int kx = 0; kx < 4; ++kx) {
            float v0 = 0.f, v1 = 0.f;
            int ix = ixb + kx;
            if ((unsigned)iy < 224u && (unsigned)ix < 224u) {
                int ci0 = 2 * h;
                v0 = x[((size_t)(n * 3 + ci0) * 224 + iy) * 224 + ix];
                if (ci0 + 1 < 3) v1 = x[((size_t)(n * 3 + ci0 + 1) * 224 + iy) * 224 + ix];
            }
            u[kx] = (u32)f2bf(v0) | ((u32)f2bf(v1) << 16);
        }
        uint4 vv; vv.x = u[0]; vv.y = u[1]; vv.z = u[2]; vv.w = u[3];
        T1[i] = vv;
    }
    if (tid < 256) {
        // 2*4*32 = 256 uint4 of weights (2048 u16)
        w1S[tid] = *(const uint4*)(w1c + (size_t)tid * 8);
    }
    __syncthreads();
    #pragma unroll
    for (int h = 0; h < 2; ++h) {
        short8 Af[MBW]; short8 Bf[NWF];
        #pragma unroll
        for (int im = 0; im < MBW; ++im) {
            int mb = wm * MBW + im;
            Af[im] = *(const short8*)(T1 + (mb * 2 + h) * 64 + lane);
        }
        #pragma unroll
        for (int inf = 0; inf < NWF; ++inf)
            Bf[inf] = *(const short8*)(w1S + (h * 4 + q) * 32 + inf * 16 + lm);
        #pragma unroll
        for (int im = 0; im < MBW; ++im)
            #pragma unroll
            for (int inf = 0; inf < NWF; ++inf)
                acc[im][inf] = mfma16(Af[im], Bf[inf], acc[im][inf]);
    }
    __syncthreads();
    #pragma unroll
    for (int inf = 0; inf < NWF; ++inf) {
        int col = inf * 16 + lm;
        float bv = bias[col];
        #pragma unroll
        for (int im = 0; im < MBW; ++im) {
            int pixb = (wm * MBW + im) * 16 + q * 4;
            #pragma unroll
            for (int r = 0; r < 4; ++r) {
                float v = fmaxf(acc[im][inf][r] + bv, 0.f);
                E[(pixb + r) * COTILE + col] = f2bf(v);
            }
        }
    }
    __syncthreads();
    for (int i = tid; i < MB * 16 * (COTILE / 8); i += 256) {
        int pix = i / (COTILE / 8), cg = i % (COTILE / 8);
        int mb = pix >> 4, m = pix & 15;
        int mbg = mbase + mb;
        int n = mbg / (H2 * NSEG), rr = mbg % (H2 * NSEG);
        int oy = rr / NSEG, ox0 = (rr % NSEG) << 4;
        int ox = ox0 + m;
        *(uint4*)(outp + (size_t)(((n * 4 + cg) * H2 + oy) * W2 + ox) * 8) =
            *(uint4*)(E + pix * COTILE + cg * 8);
    }
}

// ===========================================================================
// Generic deconv (k=4,s=2,p=1): 4 output-parity quadrants, quad = tap.
// ===========================================================================
template<int CIN, int COUT, int COPAD, int COTILE, int Hp, int Wp, int NSEG,
         int MB, int MBW, int NWF, int RELU>
__global__ __launch_bounds__(256) void deconv_mfma(
    const u16* __restrict__ in, const u16* __restrict__ dcvt,
    const float* __restrict__ bias, u16* __restrict__ outp)
{
    constexpr int CHUNKS = CIN / 8, CGI = CIN / 8, CGO = COUT / 8;
    constexpr int SLOTW = 17;
    constexpr int NF = COTILE / 16, WM = MB / MBW, WN = NF / NWF;
    static_assert(WM * WN == 4, "wave layout");
    constexpr int BPP = 64 * Hp * NSEG / MB;
    constexpr int TBu = MB * 2 * SLOTW, WBu = 4 * COTILE;
    constexpr int EBu = (MB * 16 * COTILE * 2 + 15) / 16;
    constexpr int SM = (TBu + WBu) > EBu ? (TBu + WBu) : EBu;
    __shared__ uint4 smem[SM];
    uint4* T = smem; uint4* wS = smem + TBu;
    u16* E = (u16*)smem;

    const int tid = threadIdx.x, wid = tid >> 6, lane = tid & 63;
    const int q = lane >> 4, lm = lane & 15;
    const int wm = wid / WN, wn = wid % WN;
    const int par = blockIdx.x / BPP;
    const int py = par >> 1, px = par & 1;
    const int mbase = (blockIdx.x % BPP) * MB;
    const int cobase = blockIdx.y * COTILE;

    f32x4 acc[MBW][NWF];
    #pragma unroll
    for (int a = 0; a < MBW; ++a)
        #pragma unroll
        for (int b = 0; b < NWF; ++b) {
            acc[a][b][0] = 0.f; acc[a][b][1] = 0.f;
            acc[a][b][2] = 0.f; acc[a][b][3] = 0.f;
        }

    for (int ch = 0; ch < CHUNKS; ++ch) {
        __syncthreads();
        for (int i = tid; i < TBu; i += 256) {
            int mb = i / (2 * SLOTW), r2 = i % (2 * SLOTW);
            int rr_ = r2 / SLOTW, s = r2 % SLOTW;
            int mbg = mbase + mb;
            int n = mbg / (Hp * NSEG), rm = mbg % (Hp * NSEG);
            int oyp = rm / NSEG, u0 = (rm % NSEG) << 4;
            int iy = oyp + (1 - py) - 1 + rr_;
            int ix = u0 + (1 - px) - 1 + s;
            uint4 v = {0u, 0u, 0u, 0u};
            if ((unsigned)iy < (unsigned)Hp && (unsigned)ix < (unsigned)Wp)
                v = *(const uint4*)(in + (size_t)(((n * CGI + ch) * Hp + iy) * Wp + ix) * 8);
            T[i] = v;
        }
        for (int i = tid; i < WBu; i += 256) {
            int qq = i / COTILE, co = i % COTILE;
            wS[i] = *(const uint4*)(dcvt + (size_t)((ch * 16 + par * 4 + qq) * COPAD + cobase + co) * 8);
        }
        __syncthreads();
        {
            short8 Af[MBW]; short8 Bf[NWF];
            #pragma unroll
            for (int im = 0; im < MBW; ++im) {
                int mb = wm * MBW + im;
                Af[im] = *(const short8*)(T + (mb * 2 + (1 - (q >> 1))) * SLOTW + lm + 1 - (q & 1));
            }
            #pragma unroll
            for (int inf = 0; inf < NWF; ++inf)
                Bf[inf] = *(const short8*)(wS + q * COTILE + wn * NWF * 16 + inf * 16 + lm);
            #pragma unroll
            for (int im = 0; im < MBW; ++im)
                #pragma unroll
                for (int inf = 0; inf < NWF; ++inf)
                    acc[im][inf] = mfma16(Af[im], Bf[inf], acc[im][inf]);
        }
    }
    __syncthreads();
    #pragma unroll
    for (int inf = 0; inf < NWF; ++inf) {
        int col = wn * NWF * 16 + inf * 16 + lm;
        float bv = bias[cobase + col];
        #pragma unroll
        for (int im = 0; im < MBW; ++im) {
            int pixb = (wm * MBW + im) * 16 + q * 4;
            #pragma unroll
            for (int r = 0; r < 4; ++r) {
                float v = acc[im][inf][r] + bv;
                if (RELU) v = fmaxf(v, 0.f);
                E[(pixb + r) * COTILE + col] = f2bf(v);
            }
        }
    }
    __syncthreads();
    for (int i = tid; i < MB * 16 * (COTILE / 8); i += 256) {
        int pix = i / (COTILE / 8), cg = i % (COTILE / 8);
        int mb = pix >> 4, m = pix & 15;
        int mbg = mbase + mb;
        int n = mbg / (Hp * NSEG), rm = mbg % (Hp * NSEG);
        int oyp = rm / NSEG, u0 = (rm % NSEG) << 4;
        int u = u0 + m;
        if (u < Wp) {
            int ox = 2 * u + (px ? 0 : 1);
            int oy = 2 * oyp + (py ? 0 : 1);
            *(uint4*)(outp + (size_t)(((n * CGO + cobase / 8 + cg) * (2 * Hp) + oy) * (2 * Wp) + ox) * 8) =
                *(uint4*)(E + pix * COTILE + cg * 8);
        }
    }
}

// ===========================================================================
// deconv4: COUT=3 (pad 16), fused sigmoid + recon-loss, direct NCHW f32 out.
// ===========================================================================
__global__ __launch_bounds__(256) void deconv4_mfma(
    const u16* __restrict__ in, const u16* __restrict__ dcvt,
    const float* __restrict__ bias, float* __restrict__ outp,
    const float* __restrict__ xref, float* __restrict__ racc)
{
    constexpr int Hp = 112, Wp = 112, NSEG = 7, MB = 16, MBW = 4;
    constexpr int CGI = 4, CHUNKS = 4, SLOTW = 17, COPAD = 16;
    constexpr int BPP = 64 * Hp * NSEG / MB;  // 3136
    constexpr int TBu = MB * 2 * SLOTW, WBu = 4 * 16;
    __shared__ uint4 smem[TBu + WBu];
    uint4* T = smem; uint4* wS = smem + TBu;

    const int tid = threadIdx.x, wid = tid >> 6, lane = tid & 63;
    const int q = lane >> 4, lm = lane & 15;
    const int wm = wid;  // WM=4, WN=1
    const int par = blockIdx.x / BPP;
    const int py = par >> 1, px = par & 1;
    const int mbase = (blockIdx.x % BPP) * MB;

    f32x4 acc[MBW];
    #pragma unroll
    for (int a = 0; a < MBW; ++a) { acc[a][0] = 0.f; acc[a][1] = 0.f; acc[a][2] = 0.f; acc[a][3] = 0.f; }

    for (int ch = 0; ch < CHUNKS; ++ch) {
        __syncthreads();
        for (int i = tid; i < TBu; i += 256) {
            int mb = i / (2 * SLOTW), r2 = i % (2 * SLOTW);
            int rr_ = r2 / SLOTW, s = r2 % SLOTW;
            int mbg = mbase + mb;
            int n = mbg / (Hp * NSEG), rm = mbg % (Hp * NSEG);
            int oyp = rm / NSEG, u0 = (rm % NSEG) << 4;
            int iy = oyp + (1 - py) - 1 + rr_;
            int ix = u0 + (1 - px) - 1 + s;
            uint4 v = {0u, 0u, 0u, 0u};
            if ((unsigned)iy < (unsigned)Hp && (unsigned)ix < (unsigned)Wp)
                v = *(const uint4*)(in + (size_t)(((n * CGI + ch) * Hp + iy) * Wp + ix) * 8);
            T[i] = v;
        }
        for (int i = tid; i < WBu; i += 256) {
            int qq = i / 16, co = i % 16;
            wS[i] = *(const uint4*)(dcvt + (size_t)((ch * 16 + par * 4 + qq) * COPAD + co) * 8);
        }
        __syncthreads();
        {
            short8 Af[MBW];
            #pragma unroll
            for (int im = 0; im < MBW; ++im) {
                int mb = wm * MBW + im;
                Af[im] = *(const short8*)(T + (mb * 2 + (1 - (q >> 1))) * SLOTW + lm + 1 - (q & 1));
            }
            short8 Bf = *(const short8*)(wS + q * 16 + lm);
            #pragma unroll
            for (int im = 0; im < MBW; ++im)
                acc[im] = mfma16(Af[im], Bf, acc[im]);
        }
    }
    // epilogue: sigmoid + store NCHW f32 + loss
    const int co = lm;
    float bv = (co < 3) ? bias[co] : 0.f;
    float lsum = 0.f;
    #pragma unroll
    for (int im = 0; im < MBW; ++im) {
        int mb = wm * MBW + im;
        int mbg = mbase + mb;
        int n = mbg / (Hp * NSEG), rm = mbg % (Hp * NSEG);
        int oyp = rm / NSEG, u0 = (rm % NSEG) << 4;
        if (co < 3) {
            int oy = 2 * oyp + (py ? 0 : 1);
            #pragma unroll
            for (int r = 0; r < 4; ++r) {
                int m = q * 4 + r;
                int u = u0 + m;
                int ox = 2 * u + (px ? 0 : 1);
                float v = acc[im][r] + bv;
                float s = 1.f / (1.f + expf(-v));
                size_t oi = ((size_t)(n * 3 + co) * 224 + oy) * 224 + ox;
                outp[oi] = s;
                float d = s - xref[oi];
                lsum += d * d;
            }
        }
    }
    #pragma unroll
    for (int off = 32; off > 0; off >>= 1)
        lsum += __shfl_down(lsum, off, 64);
    if (lane == 0) atomicAdd(racc, lsum);
}

// ===========================================================================
// VQ dot GEMM (bf16 MFMA): M=64, N=4000, K=12544, K split 14x.
// ===========================================================================
__global__ __launch_bounds__(256) void vq_gemm(
    const float* __restrict__ z32, const float* __restrict__ emb,
    float* __restrict__ P, float* __restrict__ normp)
{
    __shared__ uint4 As[8 * 64];
    __shared__ uint4 Bs[8 * 256];
    const int tid = threadIdx.x, wid = tid >> 6, lane = tid & 63;
    const int q = lane >> 4, lm = lane & 15;
    const int jt = blockIdx.x, ks = blockIdx.y;
    const int jg = jt * 256 + tid;
    const int jc = jg < 4000 ? jg : 3999;
    const float* brow = emb + (size_t)jc * 12544 + ks * 896;
    const int m = tid & 63, ksub = tid >> 6;
    const float* arow = z32 + (size_t)m * 12544 + ks * 896 + ksub * 16;

    f32x4 acc[4][4];
    #pragma unroll
    for (int a = 0; a < 4; ++a)
        #pragma unroll
        for (int b = 0; b < 4; ++b) {
            acc[a][b][0] = 0.f; acc[a][b][1] = 0.f; acc[a][b][2] = 0.f; acc[a][b][3] = 0.f;
        }
    float nsq = 0.f;

    for (int ch = 0; ch < 14; ++ch) {
        __syncthreads();
        {
            float4 f0 = *(const float4*)(arow + ch * 64);
            float4 f1 = *(const float4*)(arow + ch * 64 + 4);
            float4 f2 = *(const float4*)(arow + ch * 64 + 8);
            float4 f3 = *(const float4*)(arow + ch * 64 + 12);
            As[(ksub * 2 + 0) * 64 + m] = pack8(f0, f1);
            As[(ksub * 2 + 1) * 64 + m] = pack8(f2, f3);
        }
        {
            const float* bp = brow + ch * 64;
            #pragma unroll
            for (int ko = 0; ko < 8; ++ko) {
                float4 fa = *(const float4*)(bp + ko * 8);
                float4 fb = *(const float4*)(bp + ko * 8 + 4);
                nsq += fa.x * fa.x + fa.y * fa.y + fa.z * fa.z + fa.w * fa.w
                     + fb.x * fb.x + fb.y * fb.y + fb.z * fb.z + fb.w * fb.w;
                Bs[ko * 256 + tid] = pack8(fa, fb);
            }
        }
        __syncthreads();
        #pragma unroll
        for (int kk = 0; kk < 2; ++kk) {
            short8 Af[4]; short8 Bf[4];
            #pragma unroll
            for (int mf = 0; mf < 4; ++mf)
                Af[mf] = *(const short8*)(As + (kk * 4 + q) * 64 + mf * 16 + lm);
            #pragma unroll
            for (int nf = 0; nf < 4; ++nf)
                Bf[nf] = *(const short8*)(Bs + (kk * 4 + q) * 256 + wid * 64 + nf * 16 + lm);
            #pragma unroll
            for (int mf = 0; mf < 4; ++mf)
                #pragma unroll
                for (int nf = 0; nf < 4; ++nf)
                    acc[mf][nf] = mfma16(Af[mf], Bf[nf], acc[mf][nf]);
        }
    }
    #pragma unroll
    for (int mf = 0; mf < 4; ++mf)
        #pragma unroll
        for (int nf = 0; nf < 4; ++nf) {
            int j = jt * 256 + wid * 64 + nf * 16 + lm;
            if (j < 4000) {
                #pragma unroll
                for (int r = 0; r < 4; ++r) {
                    int b = mf * 16 + q * 4 + r;
                    P[(size_t)(ks * 64 + b) * 4000 + j] = acc[mf][nf][r];
                }
            }
        }
    if (jg < 4000) normp[ks * 4000 + jg] = nsq;
}

__global__ __launch_bounds__(256) void vq_argmin(
    const float* __restrict__ P, const float* __restrict__ normp,
    int* __restrict__ idxout)
{
    const int b = blockIdx.x;
    const int tid = threadIdx.x;
    float best = 3.4e38f;
    int bidx = 0x7fffffff;
    for (int j = tid; j < 4000; j += 256) {
        float dot = 0.f, nrm = 0.f;
        #pragma unroll
        for (int s = 0; s < 14; ++s) {
            dot += P[(size_t)(s * 64 + b) * 4000 + j];
            nrm += normp[s * 4000 + j];
        }
        float d = nrm - 2.f * dot;
        if (d < best) { best = d; bidx = j; }
    }
    __shared__ float sv[256];
    __shared__ int si[256];
    sv[tid] = best; si[tid] = bidx;
    __syncthreads();
    for (int off = 128; off > 0; off >>= 1) {
        if (tid < off) {
            float v2 = sv[tid + off]; int i2 = si[tid + off];
            if (v2 < sv[tid] || (v2 == sv[tid] && i2 < si[tid])) { sv[tid] = v2; si[tid] = i2; }
        }
        __syncthreads();
    }
    if (tid == 0) idxout[b] = si[0];
}

// Gather: emb row -> Qb (bf16 NC8HW8, C=64,H=W=14) + vq partial loss vs z32.
__global__ __launch_bounds__(256) void vq_gather(
    const float* __restrict__ emb, const float* __restrict__ z32,
    const int* __restrict__ idx, u16* __restrict__ Qb, float* __restrict__ vacc)
{
    const int b = blockIdx.x;
    const int code = idx[b];
    const float* e = emb + (size_t)code * 12544;
    const float* zb = z32 + (size_t)b * 12544;
    float ls = 0.f;
    for (int d = threadIdx.x; d < 12544; d += 256) {
        float ev = e[d];
        int co = d / 196, rem = d % 196;
        int y = rem / 14, xx = rem % 14;
        Qb[((size_t)((b * 8 + (co >> 3)) * 14 + y) * 14 + xx) * 8 + (co & 7)] = f2bf(ev);
        float df = ev - zb[d];
        ls += df * df;
    }
    #pragma unroll
    for (int off = 32; off > 0; off >>= 1)
        ls += __shfl_down(ls, off, 64);
    if ((threadIdx.x & 63) == 0) atomicAdd(vacc, ls);
}

__global__ void vq_finalize(const float* __restrict__ acc, float* __restrict__ tail)
{
    float recon = acc[1] * (1.f / 9633792.f);
    float vq = 1.25f * acc[0] * (1.f / 802816.f);
    tail[0] = recon + vq;
    tail[1] = recon;
    tail[2] = vq;
}

// ---------------------------------------------------------------------------
extern "C" void kernel_launch(void* const* d_in, const int* in_sizes, int n_in,
                              void* d_out, int out_size, void* d_ws, size_t ws_size,
                              hipStream_t stream)
{
    const float* x   = (const float*)d_in[0];
    const float* ew1 = (const float*)d_in[1];
    const float* eb1 = (const float*)d_in[2];
    const float* ew2 = (const float*)d_in[3];
    const float* eb2 = (const float*)d_in[4];
    const float* ew3 = (const float*)d_in[5];
    const float* eb3 = (const float*)d_in[6];
    const float* ew4 = (const float*)d_in[7];
    const float* eb4 = (const float*)d_in[8];
    const float* emb = (const float*)d_in[9];
    const float* dw1 = (const float*)d_in[10];
    const float* db1 = (const float*)d_in[11];
    const float* dw2 = (const float*)d_in[12];
    const float* db2 = (const float*)d_in[13];
    const float* dw3 = (const float*)d_in[14];
    const float* db3 = (const float*)d_in[15];
    const float* dw4 = (const float*)d_in[16];
    const float* db4 = (const float*)d_in[17];
    float* out = (float*)d_out;

    size_t off = 0;
    char* base = (char*)d_ws;
    auto nxt = [&](size_t bytes) -> char* {
        char* p = base + off;
        off = (off + bytes + 255) & ~(size_t)255;
        return p;
    };
    u16*   A1    = (u16*)nxt(25690112ull * 2);   // conv1 out bf16 NC8HW8 (64,4,112,112,8)
    u16*   A2    = (u16*)nxt(12845056ull * 2);   // conv2 out (64,8,56,56,8)
    u16*   A3    = (u16*)nxt(6422528ull * 2);    // conv3 out (64,16,28,28,8)
    float* z32   = (float*)nxt(802816ull * 4);   // conv4 out fp32 NCHW flat
    u16*   Qb    = (u16*)nxt(802816ull * 2);     // quantized bf16 NC8HW8 (also conv4 dummy out)
    float* P     = (float*)nxt(14ull * 64 * 4000 * 4);
    float* normp = (float*)nxt(14ull * 4000 * 4);
    u16*   w1c   = (u16*)nxt(2048ull * 2);       // FIX: was 512
    u16*   wc2   = (u16*)nxt(32768ull * 2);
    u16*   wc3   = (u16*)nxt(131072ull * 2);
    u16*   wc4   = (u16*)nxt(131072ull * 2);
    u16*   wd1   = (u16*)nxt(131072ull * 2);
    u16*   wd2   = (u16*)nxt(131072ull * 2);
    u16*   wd3   = (u16*)nxt(32768ull * 2);
    u16*   wd4   = (u16*)nxt(8192ull * 2);
    float* accp  = (float*)nxt(512);             // [0]=vq sum [1]=recon sum
    int*   idxp  = (int*)nxt(64 * 4);
    u16*   D1 = A3;  // aliases (producer dead before overwrite)
    u16*   D2 = A2;
    u16*   D3 = A1;

    hipMemsetAsync(accp, 0, 8, stream);

    // ---- weight prep (bf16, interleaved) ----
    prep_conv1_w <<<8,   256, 0, stream>>>(ew1, w1c);   // FIX: was 2 blocks
    prep_conv_w  <<<128, 256, 0, stream>>>(ew2, wc2, 32, 64);
    prep_conv_w  <<<512, 256, 0, stream>>>(ew3, wc3, 64, 128);
    prep_conv_w  <<<512, 256, 0, stream>>>(ew4, wc4, 128, 64);
    prep_deconv_w<<<512, 256, 0, stream>>>(dw1, wd1, 64, 128, 128);
    prep_deconv_w<<<512, 256, 0, stream>>>(dw2, wd2, 128, 64, 64);
    prep_deconv_w<<<128, 256, 0, stream>>>(dw3, wd3, 64, 32, 32);
    prep_deconv_w<<<32,  256, 0, stream>>>(dw4, wd4, 32, 3, 16);

    // ---- encoder ----
    conv1_mfma<<<3136, 256, 0, stream>>>(x, w1c, eb1, A1);
    conv_mfma<32, 64, 64, 56, 56, 4, 16, 8, 2, 1, 0>
        <<<dim3(896, 1), 256, 0, stream>>>(A1, wc2, eb2, A2, nullptr);
    conv_mfma<64, 128, 64, 28, 28, 2, 8, 4, 2, 1, 0>
        <<<dim3(448, 2), 256, 0, stream>>>(A2, wc3, eb3, A3, nullptr);
    conv_mfma<128, 64, 64, 14, 14, 1, 8, 2, 4, 0, 1>
        <<<dim3(112, 1), 256, 0, stream>>>(A3, wc4, eb4, Qb, z32);

    // ---- VQ ----
    vq_gemm  <<<dim3(16, 14), 256, 0, stream>>>(z32, emb, P, normp);
    vq_argmin<<<64, 256, 0, stream>>>(P, normp, idxp);
    vq_gather<<<64, 256, 0, stream>>>(emb, z32, idxp, Qb, accp);

    // ---- decoder ----
    deconv_mfma<64, 128, 128, 64, 14, 14, 1, 8, 4, 2, 1>
        <<<dim3(448, 2), 256, 0, stream>>>(Qb, wd1, db1, D1);
    deconv_mfma<128, 64, 64, 64, 28, 28, 2, 16, 8, 2, 1>
        <<<dim3(896, 1), 256, 0, stream>>>(D1, wd2, db2, D2);
    deconv_mfma<64, 32, 32, 32, 56, 56, 4, 16, 8, 1, 1>
        <<<dim3(3584, 1), 256, 0, stream>>>(D2, wd3, db3, D3);
    deconv4_mfma<<<12544, 256, 0, stream>>>(D3, wd4, db4, out, x, accp + 1);

    vq_finalize<<<1, 1, 0, stream>>>(accp, out + 9633792);
}

// Round 5
// 802.544 us; speedup vs baseline: 4.3229x; 1.6934x over previous
//
#include <hip/hip_runtime.h>
#include <math.h>

typedef unsigned short u16;
typedef unsigned int u32;
typedef __attribute__((ext_vector_type(8))) short short8;
typedef __attribute__((ext_vector_type(4))) float f32x4;

__device__ __forceinline__ u16 f2bf(float f) {
    u32 u = __float_as_uint(f);
    u = u + 0x7fffu + ((u >> 16) & 1u);
    return (u16)(u >> 16);
}
__device__ __forceinline__ float bf2f(u16 h) { return __uint_as_float(((u32)h) << 16); }

__device__ __forceinline__ f32x4 mfma16(short8 a, short8 b, f32x4 c) {
    return __builtin_amdgcn_mfma_f32_16x16x32_bf16(a, b, c, 0, 0, 0);
}

__device__ __forceinline__ uint4 pack8(float4 a, float4 b) {
    uint4 r;
    r.x = (u32)f2bf(a.x) | ((u32)f2bf(a.y) << 16);
    r.y = (u32)f2bf(a.z) | ((u32)f2bf(a.w) << 16);
    r.z = (u32)f2bf(b.x) | ((u32)f2bf(b.y) << 16);
    r.w = (u32)f2bf(b.z) | ((u32)f2bf(b.w) << 16);
    return r;
}

// ===========================================================================
// Weight prep: fp32 -> bf16, interleaved per-chunk layouts (run once/launch).
// ===========================================================================
// conv weights OIHW -> [ch][tap][co][ci8]
__global__ __launch_bounds__(256) void prep_conv_w(
    const float* __restrict__ w, u16* __restrict__ o, int CIN, int COUT)
{
    int i = blockIdx.x * 256 + threadIdx.x;
    int tot = CIN * 16 * COUT;
    if (i >= tot) return;
    int j = i & 7; int r = i >> 3;
    int co = r % COUT; int r2 = r / COUT;
    int tap = r2 & 15; int ch = r2 >> 4;
    int ci = ch * 8 + j;
    o[i] = f2bf(w[((size_t)co * CIN + ci) * 16 + tap]);
}
// deconv (torch in,out,kh,kw) -> [ch][py*2+px][q=ta*2+tb][co][ci8]
__global__ __launch_bounds__(256) void prep_deconv_w(
    const float* __restrict__ w, u16* __restrict__ o, int CIN, int COUT, int COPAD)
{
    int i = blockIdx.x * 256 + threadIdx.x;
    int tot = CIN * 16 * COPAD;
    if (i >= tot) return;
    int j = i & 7; int r = i >> 3;
    int co = r % COPAD; int r2 = r / COPAD;
    int t16 = r2 & 15; int ch = r2 >> 4;
    int py = t16 >> 3, px = (t16 >> 2) & 1, qq = t16 & 3;
    int ta = qq >> 1, tb = qq & 1;
    int ky = py + 2 * ta, kx = px + 2 * tb;
    int ci = ch * 8 + j;
    o[i] = (co < COUT) ? f2bf(w[(((size_t)ci * COUT + co) * 16) + ky * 4 + kx]) : (u16)0;
}
// conv1 weights -> [h][ky][co][kx*2+cp]  (ci = 2h+cp, ci=3 padded); 2048 entries
__global__ __launch_bounds__(256) void prep_conv1_w(
    const float* __restrict__ w, u16* __restrict__ o)
{
    int i = blockIdx.x * 256 + threadIdx.x;
    if (i >= 2048) return;
    int j = i & 7; int kx = j >> 1, cp = j & 1;
    int r = i >> 3;
    int co = r & 31; int r2 = r >> 5;
    int ky = r2 & 3; int h = r2 >> 2;
    int ci = 2 * h + cp;
    o[i] = (ci < 3) ? f2bf(w[((co * 3 + ci) * 16) + ky * 4 + kx]) : (u16)0;
}

// ===========================================================================
// Generic conv (k=4,s=2,p=1) implicit-GEMM MFMA kernel.
// ===========================================================================
template<int CIN, int COUT, int COTILE, int H2, int W2, int NSEG, int MB,
         int MBW, int NWF, int RELU, int STOREZ>
__global__ __launch_bounds__(256) void conv_mfma(
    const u16* __restrict__ in, const u16* __restrict__ wcvt,
    const float* __restrict__ bias, u16* __restrict__ outp,
    float* __restrict__ z32)
{
    constexpr int CHUNKS = CIN / 8, CGI = CIN / 8, CGO = COUT / 8;
    constexpr int HIN = H2 * 2, WIN = W2 * 2, SLOTW = 35;
    constexpr int NF = COTILE / 16, WM = MB / MBW, WN = NF / NWF;
    static_assert(WM * WN == 4, "wave layout");
    constexpr int TBu = MB * 4 * SLOTW, WBu = 16 * COTILE;
    constexpr int EBu = (MB * 16 * COTILE * 2 + 15) / 16;
    constexpr int SM = (TBu + WBu) > EBu ? (TBu + WBu) : EBu;
    __shared__ uint4 smem[SM];
    uint4* T = smem; uint4* wS = smem + TBu;
    u16* E = (u16*)smem;

    const int tid = threadIdx.x, wid = tid >> 6, lane = tid & 63;
    const int q = lane >> 4, lm = lane & 15;
    const int wm = wid / WN, wn = wid % WN;
    const int cobase = blockIdx.y * COTILE;
    const int mbase = blockIdx.x * MB;

    f32x4 acc[MBW][NWF];
    #pragma unroll
    for (int a = 0; a < MBW; ++a)
        #pragma unroll
        for (int b = 0; b < NWF; ++b) {
            acc[a][b][0] = 0.f; acc[a][b][1] = 0.f;
            acc[a][b][2] = 0.f; acc[a][b][3] = 0.f;
        }

    for (int ch = 0; ch < CHUNKS; ++ch) {
        __syncthreads();
        for (int i = tid; i < TBu; i += 256) {
            int mb = i / (4 * SLOTW), r2 = i % (4 * SLOTW);
            int r = r2 / SLOTW, s = r2 % SLOTW;
            int mbg = mbase + mb;
            int n = mbg / (H2 * NSEG), rr = mbg % (H2 * NSEG);
            int oy = rr / NSEG, ox0 = (rr % NSEG) << 4;
            int iy = 2 * oy - 1 + r, ix = 2 * ox0 - 1 + s;
            uint4 v = {0u, 0u, 0u, 0u};
            if ((unsigned)iy < (unsigned)HIN && (unsigned)ix < (unsigned)WIN)
                v = *(const uint4*)(in + (size_t)(((n * CGI + ch) * HIN + iy) * WIN + ix) * 8);
            T[i] = v;
        }
        for (int i = tid; i < WBu; i += 256) {
            int tap = i / COTILE, co = i % COTILE;
            wS[i] = *(const uint4*)(wcvt + (size_t)((ch * 16 + tap) * COUT + cobase + co) * 8);
        }
        __syncthreads();
        #pragma unroll
        for (int ky = 0; ky < 4; ++ky) {
            short8 Af[MBW]; short8 Bf[NWF];
            #pragma unroll
            for (int im = 0; im < MBW; ++im) {
                int mb = wm * MBW + im;
                Af[im] = *(const short8*)(T + (mb * 4 + ky) * SLOTW + 2 * lm + q);
            }
            #pragma unroll
            for (int inf = 0; inf < NWF; ++inf)
                Bf[inf] = *(const short8*)(wS + (ky * 4 + q) * COTILE + wn * NWF * 16 + inf * 16 + lm);
            #pragma unroll
            for (int im = 0; im < MBW; ++im)
                #pragma unroll
                for (int inf = 0; inf < NWF; ++inf)
                    acc[im][inf] = mfma16(Af[im], Bf[inf], acc[im][inf]);
        }
    }
    __syncthreads();
    #pragma unroll
    for (int inf = 0; inf < NWF; ++inf) {
        int col = wn * NWF * 16 + inf * 16 + lm;
        float bv = bias[cobase + col];
        #pragma unroll
        for (int im = 0; im < MBW; ++im) {
            int pixb = (wm * MBW + im) * 16 + q * 4;
            #pragma unroll
            for (int r = 0; r < 4; ++r) {
                float v = acc[im][inf][r] + bv;
                if (RELU) v = fmaxf(v, 0.f);
                E[(pixb + r) * COTILE + col] = f2bf(v);
            }
        }
    }
    __syncthreads();
    for (int i = tid; i < MB * 16 * (COTILE / 8); i += 256) {
        int pix = i / (COTILE / 8), cg = i % (COTILE / 8);
        int mb = pix >> 4, m = pix & 15;
        int mbg = mbase + mb;
        int n = mbg / (H2 * NSEG), rr = mbg % (H2 * NSEG);
        int oy = rr / NSEG, ox0 = (rr % NSEG) << 4;
        int ox = ox0 + m;
        if (ox < W2)
            *(uint4*)(outp + (size_t)(((n * CGO + cobase / 8 + cg) * H2 + oy) * W2 + ox) * 8) =
                *(uint4*)(E + pix * COTILE + cg * 8);
    }
    if (STOREZ) {
        for (int i = tid; i < MB * 16 * COTILE; i += 256) {
            int pix = i / COTILE, co = i % COTILE;
            int mb = pix >> 4, m = pix & 15;
            int mbg = mbase + mb;
            int n = mbg / (H2 * NSEG), rr = mbg % (H2 * NSEG);
            int oy = rr / NSEG, ox0 = (rr % NSEG) << 4;
            int ox = ox0 + m;
            if (ox < W2)
                z32[(size_t)((n * COUT + cobase + co) * H2 + oy) * W2 + ox] =
                    bf2f(E[pix * COTILE + co]);
        }
    }
}

// ===========================================================================
// conv1 (CIN=3) special: quad = ky, j = kx*2+cp (ci=2h+cp), 2 halves h.
// ===========================================================================
__global__ __launch_bounds__(256) void conv1_mfma(
    const float* __restrict__ x, const u16* __restrict__ w1c,
    const float* __restrict__ bias, u16* __restrict__ outp)
{
    constexpr int MB = 16, MBW = 4, NWF = 2, COTILE = 32, W2 = 112, H2 = 112, NSEG = 7;
    constexpr int TBu = MB * 2 * 64, WBu = 256;
    __shared__ uint4 smem[TBu + WBu];
    uint4* T1 = smem; uint4* w1S = smem + TBu;
    u16* E = (u16*)smem;

    const int tid = threadIdx.x, wid = tid >> 6, lane = tid & 63;
    const int q = lane >> 4, lm = lane & 15;
    const int wm = wid;
    const int mbase = blockIdx.x * MB;

    f32x4 acc[MBW][NWF];
    #pragma unroll
    for (int a = 0; a < MBW; ++a)
        #pragma unroll
        for (int b = 0; b < NWF; ++b) {
            acc[a][b][0] = 0.f; acc[a][b][1] = 0.f;
            acc[a][b][2] = 0.f; acc[a][b][3] = 0.f;
        }

    for (int i = tid; i < TBu; i += 256) {
        int mb = i >> 7; int r = i & 127;
        int h = r >> 6; int r2 = r & 63;
        int ky = r2 >> 4; int m = r2 & 15;
        int mbg = mbase + mb;
        int n = mbg / (H2 * NSEG), rr = mbg % (H2 * NSEG);
        int oy = rr / NSEG, ox0 = (rr % NSEG) << 4;
        int iy = 2 * oy - 1 + ky;
        int ixb = 2 * (ox0 + m) - 1;
        u32 u[4];
        #pragma unroll
        for (int kx = 0; kx < 4; ++kx) {
            float v0 = 0.f, v1 = 0.f;
            int ix = ixb + kx;
            if ((unsigned)iy < 224u && (unsigned)ix < 224u) {
                int ci0 = 2 * h;
                v0 = x[((size_t)(n * 3 + ci0) * 224 + iy) * 224 + ix];
                if (ci0 + 1 < 3) v1 = x[((size_t)(n * 3 + ci0 + 1) * 224 + iy) * 224 + ix];
            }
            u[kx] = (u32)f2bf(v0) | ((u32)f2bf(v1) << 16);
        }
        uint4 vv; vv.x = u[0]; vv.y = u[1]; vv.z = u[2]; vv.w = u[3];
        T1[i] = vv;
    }
    if (tid < 256) {
        w1S[tid] = *(const uint4*)(w1c + (size_t)tid * 8);
    }
    __syncthreads();
    #pragma unroll
    for (int h = 0; h < 2; ++h) {
        short8 Af[MBW]; short8 Bf[NWF];
        #pragma unroll
        for (int im = 0; im < MBW; ++im) {
            int mb = wm * MBW + im;
            Af[im] = *(const short8*)(T1 + (mb * 2 + h) * 64 + lane);
        }
        #pragma unroll
        for (int inf = 0; inf < NWF; ++inf)
            Bf[inf] = *(const short8*)(w1S + (h * 4 + q) * 32 + inf * 16 + lm);
        #pragma unroll
        for (int im = 0; im < MBW; ++im)
            #pragma unroll
            for (int inf = 0; inf < NWF; ++inf)
                acc[im][inf] = mfma16(Af[im], Bf[inf], acc[im][inf]);
    }
    __syncthreads();
    #pragma unroll
    for (int inf = 0; inf < NWF; ++inf) {
        int col = inf * 16 + lm;
        float bv = bias[col];
        #pragma unroll
        for (int im = 0; im < MBW; ++im) {
            int pixb = (wm * MBW + im) * 16 + q * 4;
            #pragma unroll
            for (int r = 0; r < 4; ++r) {
                float v = fmaxf(acc[im][inf][r] + bv, 0.f);
                E[(pixb + r) * COTILE + col] = f2bf(v);
            }
        }
    }
    __syncthreads();
    for (int i = tid; i < MB * 16 * (COTILE / 8); i += 256) {
        int pix = i / (COTILE / 8), cg = i % (COTILE / 8);
        int mb = pix >> 4, m = pix & 15;
        int mbg = mbase + mb;
        int n = mbg / (H2 * NSEG), rr = mbg % (H2 * NSEG);
        int oy = rr / NSEG, ox0 = (rr % NSEG) << 4;
        int ox = ox0 + m;
        *(uint4*)(outp + (size_t)(((n * 4 + cg) * H2 + oy) * W2 + ox) * 8) =
            *(uint4*)(E + pix * COTILE + cg * 8);
    }
}

// ===========================================================================
// Generic deconv (k=4,s=2,p=1): 4 output-parity quadrants, quad = tap.
// ===========================================================================
template<int CIN, int COUT, int COPAD, int COTILE, int Hp, int Wp, int NSEG,
         int MB, int MBW, int NWF, int RELU>
__global__ __launch_bounds__(256) void deconv_mfma(
    const u16* __restrict__ in, const u16* __restrict__ dcvt,
    const float* __restrict__ bias, u16* __restrict__ outp)
{
    constexpr int CHUNKS = CIN / 8, CGI = CIN / 8, CGO = COUT / 8;
    constexpr int SLOTW = 17;
    constexpr int NF = COTILE / 16, WM = MB / MBW, WN = NF / NWF;
    static_assert(WM * WN == 4, "wave layout");
    constexpr int BPP = 64 * Hp * NSEG / MB;
    constexpr int TBu = MB * 2 * SLOTW, WBu = 4 * COTILE;
    constexpr int EBu = (MB * 16 * COTILE * 2 + 15) / 16;
    constexpr int SM = (TBu + WBu) > EBu ? (TBu + WBu) : EBu;
    __shared__ uint4 smem[SM];
    uint4* T = smem; uint4* wS = smem + TBu;
    u16* E = (u16*)smem;

    const int tid = threadIdx.x, wid = tid >> 6, lane = tid & 63;
    const int q = lane >> 4, lm = lane & 15;
    const int wm = wid / WN, wn = wid % WN;
    const int par = blockIdx.x / BPP;
    const int py = par >> 1, px = par & 1;
    const int mbase = (blockIdx.x % BPP) * MB;
    const int cobase = blockIdx.y * COTILE;

    f32x4 acc[MBW][NWF];
    #pragma unroll
    for (int a = 0; a < MBW; ++a)
        #pragma unroll
        for (int b = 0; b < NWF; ++b) {
            acc[a][b][0] = 0.f; acc[a][b][1] = 0.f;
            acc[a][b][2] = 0.f; acc[a][b][3] = 0.f;
        }

    for (int ch = 0; ch < CHUNKS; ++ch) {
        __syncthreads();
        for (int i = tid; i < TBu; i += 256) {
            int mb = i / (2 * SLOTW), r2 = i % (2 * SLOTW);
            int rr_ = r2 / SLOTW, s = r2 % SLOTW;
            int mbg = mbase + mb;
            int n = mbg / (Hp * NSEG), rm = mbg % (Hp * NSEG);
            int oyp = rm / NSEG, u0 = (rm % NSEG) << 4;
            int iy = oyp + (1 - py) - 1 + rr_;
            int ix = u0 + (1 - px) - 1 + s;
            uint4 v = {0u, 0u, 0u, 0u};
            if ((unsigned)iy < (unsigned)Hp && (unsigned)ix < (unsigned)Wp)
                v = *(const uint4*)(in + (size_t)(((n * CGI + ch) * Hp + iy) * Wp + ix) * 8);
            T[i] = v;
        }
        for (int i = tid; i < WBu; i += 256) {
            int qq = i / COTILE, co = i % COTILE;
            wS[i] = *(const uint4*)(dcvt + (size_t)((ch * 16 + par * 4 + qq) * COPAD + cobase + co) * 8);
        }
        __syncthreads();
        {
            short8 Af[MBW]; short8 Bf[NWF];
            #pragma unroll
            for (int im = 0; im < MBW; ++im) {
                int mb = wm * MBW + im;
                Af[im] = *(const short8*)(T + (mb * 2 + (1 - (q >> 1))) * SLOTW + lm + 1 - (q & 1));
            }
            #pragma unroll
            for (int inf = 0; inf < NWF; ++inf)
                Bf[inf] = *(const short8*)(wS + q * COTILE + wn * NWF * 16 + inf * 16 + lm);
            #pragma unroll
            for (int im = 0; im < MBW; ++im)
                #pragma unroll
                for (int inf = 0; inf < NWF; ++inf)
                    acc[im][inf] = mfma16(Af[im], Bf[inf], acc[im][inf]);
        }
    }
    __syncthreads();
    #pragma unroll
    for (int inf = 0; inf < NWF; ++inf) {
        int col = wn * NWF * 16 + inf * 16 + lm;
        float bv = bias[cobase + col];
        #pragma unroll
        for (int im = 0; im < MBW; ++im) {
            int pixb = (wm * MBW + im) * 16 + q * 4;
            #pragma unroll
            for (int r = 0; r < 4; ++r) {
                float v = acc[im][inf][r] + bv;
                if (RELU) v = fmaxf(v, 0.f);
                E[(pixb + r) * COTILE + col] = f2bf(v);
            }
        }
    }
    __syncthreads();
    for (int i = tid; i < MB * 16 * (COTILE / 8); i += 256) {
        int pix = i / (COTILE / 8), cg = i % (COTILE / 8);
        int mb = pix >> 4, m = pix & 15;
        int mbg = mbase + mb;
        int n = mbg / (Hp * NSEG), rm = mbg % (Hp * NSEG);
        int oyp = rm / NSEG, u0 = (rm % NSEG) << 4;
        int u = u0 + m;
        if (u < Wp) {
            int ox = 2 * u + (px ? 0 : 1);
            int oy = 2 * oyp + (py ? 0 : 1);
            *(uint4*)(outp + (size_t)(((n * CGO + cobase / 8 + cg) * (2 * Hp) + oy) * (2 * Wp) + ox) * 8) =
                *(uint4*)(E + pix * COTILE + cg * 8);
        }
    }
}

// ===========================================================================
// deconv4 (rewritten): one block computes ALL 4 parity quadrants of its
// 256-pixel tile. Tile halo (3 rows x 18 cols) staged once per ci-chunk;
// weights staged once. Coalesced float2 stores; loss via per-block partial
// (NO same-address atomics — that was 650 us of round-4's runtime).
// ===========================================================================
__global__ __launch_bounds__(256) void deconv4_mfma(
    const u16* __restrict__ in, const u16* __restrict__ dcvt,
    const float* __restrict__ bias, float* __restrict__ outp,
    const float* __restrict__ xref, float* __restrict__ bpart)
{
    constexpr int Hp = 112, Wp = 112, NSEG = 7, MB = 16, MBW = 4;
    constexpr int CGI = 4, CHUNKS = 4, COPAD = 16;
    constexpr int TROW = 3, TCOL = 18;
    constexpr int TBu = MB * TROW * TCOL;   // 864 uint4
    constexpr int WBu = CHUNKS * 16 * COPAD / 16 * 16;  // 1024 uint4
    __shared__ uint4 smem[TBu + 1024];
    __shared__ float red[4];
    uint4* T = smem; uint4* wS = smem + TBu;

    const int tid = threadIdx.x, wid = tid >> 6, lane = tid & 63;
    const int q = lane >> 4, lm = lane & 15;
    const int wm = wid;  // 4 waves, each owns 4 macro-blocks
    const int mbase = blockIdx.x * MB;

    f32x4 acc[4][MBW];  // [par][im]
    #pragma unroll
    for (int p = 0; p < 4; ++p)
        #pragma unroll
        for (int a = 0; a < MBW; ++a) {
            acc[p][a][0] = 0.f; acc[p][a][1] = 0.f; acc[p][a][2] = 0.f; acc[p][a][3] = 0.f;
        }

    // stage all weights once (1024 uint4 = contiguous)
    for (int i = tid; i < 1024; i += 256)
        wS[i] = *(const uint4*)(dcvt + (size_t)i * 8);

    for (int ch = 0; ch < CHUNKS; ++ch) {
        __syncthreads();
        for (int i = tid; i < TBu; i += 256) {
            int mb = i / (TROW * TCOL), r2 = i % (TROW * TCOL);
            int r = r2 / TCOL, s = r2 % TCOL;
            int mbg = mbase + mb;
            int n = mbg / (Hp * NSEG), rm = mbg % (Hp * NSEG);
            int oyp = rm / NSEG, u0 = (rm % NSEG) << 4;
            int iy = oyp - 1 + r;          // rows oyp-1 .. oyp+1
            int ix = u0 - 1 + s;           // cols u0-1 .. u0+16
            uint4 v = {0u, 0u, 0u, 0u};
            if ((unsigned)iy < (unsigned)Hp && (unsigned)ix < (unsigned)Wp)
                v = *(const uint4*)(in + (size_t)(((n * CGI + ch) * Hp + iy) * Wp + ix) * 8);
            T[i] = v;
        }
        __syncthreads();
        #pragma unroll
        for (int par = 0; par < 4; ++par) {
            const int py = par >> 1, px = par & 1;
            short8 Bf = *(const short8*)(wS + (ch * 16 + par * 4 + q) * 16 + lm);
            #pragma unroll
            for (int im = 0; im < MBW; ++im) {
                int mb = wm * MBW + im;
                // row = 2 - py - (q>>1); col = lm + 2 - px - (q&1)
                short8 Af = *(const short8*)(T + (mb * TROW + (2 - py - (q >> 1))) * TCOL
                                             + lm + 2 - px - (q & 1));
                acc[par][im] = mfma16(Af, Bf, acc[par][im]);
            }
        }
    }

    // epilogue: per thread holds col=lm for 4 parities.
    // oy=2*oyp   row: {par3 at ox=2u, par2 at ox=2u+1}
    // oy=2*oyp+1 row: {par1 at ox=2u, par0 at ox=2u+1}
    const int co = lm;
    float bv = (co < 3) ? bias[co] : 0.f;
    float lsum = 0.f;
    if (co < 3) {
        #pragma unroll
        for (int im = 0; im < MBW; ++im) {
            int mbg = mbase + wm * MBW + im;
            int n = mbg / (Hp * NSEG), rm = mbg % (Hp * NSEG);
            int oyp = rm / NSEG, u0 = (rm % NSEG) << 4;
            #pragma unroll
            for (int r = 0; r < 4; ++r) {
                int u = u0 + q * 4 + r;
                float v3 = acc[3][im][r] + bv;
                float v2 = acc[2][im][r] + bv;
                float v1 = acc[1][im][r] + bv;
                float v0 = acc[0][im][r] + bv;
                float s3 = 1.f / (1.f + expf(-v3));
                float s2 = 1.f / (1.f + expf(-v2));
                float s1 = 1.f / (1.f + expf(-v1));
                float s0 = 1.f / (1.f + expf(-v0));
                size_t rowA = ((size_t)(n * 3 + co) * 224 + 2 * oyp) * 224 + 2 * u;
                size_t rowB = rowA + 224;
                float2 xa = *(const float2*)(xref + rowA);
                float2 xb = *(const float2*)(xref + rowB);
                *(float2*)(outp + rowA) = make_float2(s3, s2);
                *(float2*)(outp + rowB) = make_float2(s1, s0);
                float d0 = s3 - xa.x, d1 = s2 - xa.y, d2 = s1 - xb.x, d3 = s0 - xb.y;
                lsum += d0 * d0 + d1 * d1 + d2 * d2 + d3 * d3;
            }
        }
    }
    #pragma unroll
    for (int off = 32; off > 0; off >>= 1)
        lsum += __shfl_down(lsum, off, 64);
    if (lane == 0) red[wid] = lsum;
    __syncthreads();
    if (tid == 0)
        bpart[blockIdx.x] = red[0] + red[1] + red[2] + red[3];
}

// ===========================================================================
// VQ dot GEMM (bf16 MFMA): M=64, N=4000, K=12544, K split 14x.
// ===========================================================================
__global__ __launch_bounds__(256) void vq_gemm(
    const float* __restrict__ z32, const float* __restrict__ emb,
    float* __restrict__ P, float* __restrict__ normp)
{
    __shared__ uint4 As[8 * 64];
    __shared__ uint4 Bs[8 * 256];
    const int tid = threadIdx.x, wid = tid >> 6, lane = tid & 63;
    const int q = lane >> 4, lm = lane & 15;
    const int jt = blockIdx.x, ks = blockIdx.y;
    const int jg = jt * 256 + tid;
    const int jc = jg < 4000 ? jg : 3999;
    const float* brow = emb + (size_t)jc * 12544 + ks * 896;
    const int m = tid & 63, ksub = tid >> 6;
    const float* arow = z32 + (size_t)m * 12544 + ks * 896 + ksub * 16;

    f32x4 acc[4][4];
    #pragma unroll
    for (int a = 0; a < 4; ++a)
        #pragma unroll
        for (int b = 0; b < 4; ++b) {
            acc[a][b][0] = 0.f; acc[a][b][1] = 0.f; acc[a][b][2] = 0.f; acc[a][b][3] = 0.f;
        }
    float nsq = 0.f;

    for (int ch = 0; ch < 14; ++ch) {
        __syncthreads();
        {
            float4 f0 = *(const float4*)(arow + ch * 64);
            float4 f1 = *(const float4*)(arow + ch * 64 + 4);
            float4 f2 = *(const float4*)(arow + ch * 64 + 8);
            float4 f3 = *(const float4*)(arow + ch * 64 + 12);
            As[(ksub * 2 + 0) * 64 + m] = pack8(f0, f1);
            As[(ksub * 2 + 1) * 64 + m] = pack8(f2, f3);
        }
        {
            const float* bp = brow + ch * 64;
            #pragma unroll
            for (int ko = 0; ko < 8; ++ko) {
                float4 fa = *(const float4*)(bp + ko * 8);
                float4 fb = *(const float4*)(bp + ko * 8 + 4);
                nsq += fa.x * fa.x + fa.y * fa.y + fa.z * fa.z + fa.w * fa.w
                     + fb.x * fb.x + fb.y * fb.y + fb.z * fb.z + fb.w * fb.w;
                Bs[ko * 256 + tid] = pack8(fa, fb);
            }
        }
        __syncthreads();
        #pragma unroll
        for (int kk = 0; kk < 2; ++kk) {
            short8 Af[4]; short8 Bf[4];
            #pragma unroll
            for (int mf = 0; mf < 4; ++mf)
                Af[mf] = *(const short8*)(As + (kk * 4 + q) * 64 + mf * 16 + lm);
            #pragma unroll
            for (int nf = 0; nf < 4; ++nf)
                Bf[nf] = *(const short8*)(Bs + (kk * 4 + q) * 256 + wid * 64 + nf * 16 + lm);
            #pragma unroll
            for (int mf = 0; mf < 4; ++mf)
                #pragma unroll
                for (int nf = 0; nf < 4; ++nf)
                    acc[mf][nf] = mfma16(Af[mf], Bf[nf], acc[mf][nf]);
        }
    }
    #pragma unroll
    for (int mf = 0; mf < 4; ++mf)
        #pragma unroll
        for (int nf = 0; nf < 4; ++nf) {
            int j = jt * 256 + wid * 64 + nf * 16 + lm;
            if (j < 4000) {
                #pragma unroll
                for (int r = 0; r < 4; ++r) {
                    int b = mf * 16 + q * 4 + r;
                    P[(size_t)(ks * 64 + b) * 4000 + j] = acc[mf][nf][r];
                }
            }
        }
    if (jg < 4000) normp[ks * 4000 + jg] = nsq;
}

__global__ __launch_bounds__(256) void vq_argmin(
    const float* __restrict__ P, const float* __restrict__ normp,
    int* __restrict__ idxout)
{
    const int b = blockIdx.x;
    const int tid = threadIdx.x;
    float best = 3.4e38f;
    int bidx = 0x7fffffff;
    for (int j = tid; j < 4000; j += 256) {
        float dot = 0.f, nrm = 0.f;
        #pragma unroll
        for (int s = 0; s < 14; ++s) {
            dot += P[(size_t)(s * 64 + b) * 4000 + j];
            nrm += normp[s * 4000 + j];
        }
        float d = nrm - 2.f * dot;
        if (d < best) { best = d; bidx = j; }
    }
    __shared__ float sv[256];
    __shared__ int si[256];
    sv[tid] = best; si[tid] = bidx;
    __syncthreads();
    for (int off = 128; off > 0; off >>= 1) {
        if (tid < off) {
            float v2 = sv[tid + off]; int i2 = si[tid + off];
            if (v2 < sv[tid] || (v2 == sv[tid] && i2 < si[tid])) { sv[tid] = v2; si[tid] = i2; }
        }
        __syncthreads();
    }
    if (tid == 0) idxout[b] = si[0];
}

// Gather: emb row -> Qb (bf16 NC8HW8, C=64,H=W=14) + vq partial loss vs z32.
__global__ __launch_bounds__(256) void vq_gather(
    const float* __restrict__ emb, const float* __restrict__ z32,
    const int* __restrict__ idx, u16* __restrict__ Qb, float* __restrict__ vacc)
{
    const int b = blockIdx.x;
    const int code = idx[b];
    const float* e = emb + (size_t)code * 12544;
    const float* zb = z32 + (size_t)b * 12544;
    float ls = 0.f;
    for (int d = threadIdx.x; d < 12544; d += 256) {
        float ev = e[d];
        int co = d / 196, rem = d % 196;
        int y = rem / 14, xx = rem % 14;
        Qb[((size_t)((b * 8 + (co >> 3)) * 14 + y) * 14 + xx) * 8 + (co & 7)] = f2bf(ev);
        float df = ev - zb[d];
        ls += df * df;
    }
    #pragma unroll
    for (int off = 32; off > 0; off >>= 1)
        ls += __shfl_down(ls, off, 64);
    if ((threadIdx.x & 63) == 0) atomicAdd(vacc, ls);
}

// Final: sum 3136 per-block recon partials + vq accumulator -> loss tail.
__global__ __launch_bounds__(256) void reduce_final(
    const float* __restrict__ bpart, const float* __restrict__ vacc,
    float* __restrict__ tail)
{
    const int tid = threadIdx.x;
    float s = 0.f;
    for (int i = tid; i < 3136; i += 256) s += bpart[i];
    #pragma unroll
    for (int off = 32; off > 0; off >>= 1)
        s += __shfl_down(s, off, 64);
    __shared__ float red[4];
    if ((tid & 63) == 0) red[tid >> 6] = s;
    __syncthreads();
    if (tid == 0) {
        float rsum = red[0] + red[1] + red[2] + red[3];
        float recon = rsum * (1.f / 9633792.f);
        float vq = 1.25f * vacc[0] * (1.f / 802816.f);
        tail[0] = recon + vq;
        tail[1] = recon;
        tail[2] = vq;
    }
}

// ---------------------------------------------------------------------------
extern "C" void kernel_launch(void* const* d_in, const int* in_sizes, int n_in,
                              void* d_out, int out_size, void* d_ws, size_t ws_size,
                              hipStream_t stream)
{
    const float* x   = (const float*)d_in[0];
    const float* ew1 = (const float*)d_in[1];
    const float* eb1 = (const float*)d_in[2];
    const float* ew2 = (const float*)d_in[3];
    const float* eb2 = (const float*)d_in[4];
    const float* ew3 = (const float*)d_in[5];
    const float* eb3 = (const float*)d_in[6];
    const float* ew4 = (const float*)d_in[7];
    const float* eb4 = (const float*)d_in[8];
    const float* emb = (const float*)d_in[9];
    const float* dw1 = (const float*)d_in[10];
    const float* db1 = (const float*)d_in[11];
    const float* dw2 = (const float*)d_in[12];
    const float* db2 = (const float*)d_in[13];
    const float* dw3 = (const float*)d_in[14];
    const float* db3 = (const float*)d_in[15];
    const float* dw4 = (const float*)d_in[16];
    const float* db4 = (const float*)d_in[17];
    float* out = (float*)d_out;

    size_t off = 0;
    char* base = (char*)d_ws;
    auto nxt = [&](size_t bytes) -> char* {
        char* p = base + off;
        off = (off + bytes + 255) & ~(size_t)255;
        return p;
    };
    u16*   A1    = (u16*)nxt(25690112ull * 2);
    u16*   A2    = (u16*)nxt(12845056ull * 2);
    u16*   A3    = (u16*)nxt(6422528ull * 2);
    float* z32   = (float*)nxt(802816ull * 4);
    u16*   Qb    = (u16*)nxt(802816ull * 2);
    float* P     = (float*)nxt(14ull * 64 * 4000 * 4);
    float* normp = (float*)nxt(14ull * 4000 * 4);
    u16*   w1c   = (u16*)nxt(2048ull * 2);
    u16*   wc2   = (u16*)nxt(32768ull * 2);
    u16*   wc3   = (u16*)nxt(131072ull * 2);
    u16*   wc4   = (u16*)nxt(131072ull * 2);
    u16*   wd1   = (u16*)nxt(131072ull * 2);
    u16*   wd2   = (u16*)nxt(131072ull * 2);
    u16*   wd3   = (u16*)nxt(32768ull * 2);
    u16*   wd4   = (u16*)nxt(8192ull * 2);
    float* accp  = (float*)nxt(512);             // [0]=vq sum
    int*   idxp  = (int*)nxt(64 * 4);
    float* bpart = (float*)nxt(3136ull * 4);     // deconv4 per-block recon partials
    u16*   D1 = A3;
    u16*   D2 = A2;
    u16*   D3 = A1;

    hipMemsetAsync(accp, 0, 8, stream);

    // ---- weight prep ----
    prep_conv1_w <<<8,   256, 0, stream>>>(ew1, w1c);
    prep_conv_w  <<<128, 256, 0, stream>>>(ew2, wc2, 32, 64);
    prep_conv_w  <<<512, 256, 0, stream>>>(ew3, wc3, 64, 128);
    prep_conv_w  <<<512, 256, 0, stream>>>(ew4, wc4, 128, 64);
    prep_deconv_w<<<512, 256, 0, stream>>>(dw1, wd1, 64, 128, 128);
    prep_deconv_w<<<512, 256, 0, stream>>>(dw2, wd2, 128, 64, 64);
    prep_deconv_w<<<128, 256, 0, stream>>>(dw3, wd3, 64, 32, 32);
    prep_deconv_w<<<32,  256, 0, stream>>>(dw4, wd4, 32, 3, 16);

    // ---- encoder ----
    conv1_mfma<<<3136, 256, 0, stream>>>(x, w1c, eb1, A1);
    conv_mfma<32, 64, 64, 56, 56, 4, 16, 8, 2, 1, 0>
        <<<dim3(896, 1), 256, 0, stream>>>(A1, wc2, eb2, A2, nullptr);
    conv_mfma<64, 128, 64, 28, 28, 2, 8, 4, 2, 1, 0>
        <<<dim3(448, 2), 256, 0, stream>>>(A2, wc3, eb3, A3, nullptr);
    conv_mfma<128, 64, 64, 14, 14, 1, 8, 2, 4, 0, 1>
        <<<dim3(112, 1), 256, 0, stream>>>(A3, wc4, eb4, Qb, z32);

    // ---- VQ ----
    vq_gemm  <<<dim3(16, 14), 256, 0, stream>>>(z32, emb, P, normp);
    vq_argmin<<<64, 256, 0, stream>>>(P, normp, idxp);
    vq_gather<<<64, 256, 0, stream>>>(emb, z32, idxp, Qb, accp);

    // ---- decoder ----
    deconv_mfma<64, 128, 128, 64, 14, 14, 1, 8, 4, 2, 1>
        <<<dim3(448, 2), 256, 0, stream>>>(Qb, wd1, db1, D1);
    deconv_mfma<128, 64, 64, 64, 28, 28, 2, 16, 8, 2, 1>
        <<<dim3(896, 1), 256, 0, stream>>>(D1, wd2, db2, D2);
    deconv_mfma<64, 32, 32, 32, 56, 56, 4, 16, 8, 1, 1>
        <<<dim3(3584, 1), 256, 0, stream>>>(D2, wd3, db3, D3);
    deconv4_mfma<<<3136, 256, 0, stream>>>(D3, wd4, db4, out, x, bpart);

    reduce_final<<<1, 256, 0, stream>>>(bpart, accp, out + 9633792);
}